// Round 6
// baseline (1417.101 us; speedup 1.0000x reference)
//
#include <hip/hip_runtime.h>

#define FEAT 128
#define RANGE 12800
#define NSLICE 64

typedef _Float16 half8 __attribute__((ext_vector_type(8)));
typedef float f32x4 __attribute__((ext_vector_type(4)));

// ---------- hist: src & dst partial histograms in one dispatch, ushort-packed ----------
__global__ __launch_bounds__(1024) void hist_kernel(const int* __restrict__ src,
                                                    const int* __restrict__ dst,
                                                    unsigned* __restrict__ partialD,
                                                    unsigned* __restrict__ partialS,
                                                    int E, int NP) {
    __shared__ unsigned hpk[RANGE / 2];
    int per = (NP / RANGE) * NSLICE;
    int b = blockIdx.x;
    int halfsel = b / per;           // 0 = dst histogram, 1 = src histogram
    int q = b % per;
    int r = q / NSLICE;
    int s = q % NSLICE;
    const int* arr = halfsel ? src : dst;
    unsigned* out = halfsel ? partialS : partialD;
    int v0 = r * RANGE;
    int tid = threadIdx.x;
    for (int i = tid; i < RANGE / 2; i += 1024) hpk[i] = 0;
    __syncthreads();
    int e0 = (int)((long long)E * s / NSLICE);
    int e1 = (int)((long long)E * (s + 1) / NSLICE);
    for (int e = e0 + tid; e < e1; e += 1024) {
        unsigned d = (unsigned)(arr[e] - v0);
        if (d < RANGE) atomicAdd(&hpk[d >> 1], (d & 1) ? 65536u : 1u);
    }
    __syncthreads();
    size_t wbase = ((size_t)s * NP + v0) >> 1;
    for (int i = tid; i < RANGE / 2; i += 1024) out[wbase + i] = hpk[i];
}

// ---------- prep1: blocks [0,sb): scanp1 (slice sums + norms + blockSums)
//                   blocks [sb, sb+320): W fp16 value+residual transpose + bias concat ----------
__global__ __launch_bounds__(256) void prep1_kernel(const unsigned short* __restrict__ pD,
                                                    const unsigned short* __restrict__ pS,
                                                    int* __restrict__ blockSums,
                                                    float* __restrict__ ns,
                                                    float* __restrict__ nd,
                                                    const float* __restrict__ Wa,
                                                    const float* __restrict__ Wb,
                                                    const float* __restrict__ Wc,
                                                    const float* __restrict__ Wd,
                                                    const float* __restrict__ We,
                                                    const float* __restrict__ Ba,
                                                    const float* __restrict__ Bb,
                                                    const float* __restrict__ Bc,
                                                    const float* __restrict__ Bd,
                                                    const float* __restrict__ Be,
                                                    _Float16* __restrict__ w16t,
                                                    _Float16* __restrict__ wrt,
                                                    float* __restrict__ bcat,
                                                    int NP, int n, int sb) {
    int tid = threadIdx.x;
    int b = blockIdx.x;
    if (b < sb) {
        __shared__ int buf[256];
        int v = b * 256 + tid;
        int ssum = 0, osum = 0;
        #pragma unroll
        for (int s = 0; s < NSLICE; ++s) {
            ssum += pD[(size_t)s * NP + v];
            osum += pS[(size_t)s * NP + v];
        }
        if (v < n) {
            ns[v] = 1.0f / sqrtf((float)(osum < 1 ? 1 : osum));
            nd[v] = 1.0f / sqrtf((float)(ssum < 1 ? 1 : ssum));
        }
        buf[tid] = ssum;
        __syncthreads();
        #pragma unroll
        for (int off = 1; off < 256; off <<= 1) {
            int t = (tid >= off) ? buf[tid - off] : 0;
            __syncthreads();
            buf[tid] += t;
            __syncthreads();
        }
        if (tid == 255) blockSums[b] = buf[255];
    } else {
        int gid = (b - sb) * 256 + tid;              // 0 .. 81919
        int l = gid >> 14;
        int idx = gid & 16383;
        int col = idx >> 7;
        int k = idx & 127;
        const float* Wp = (l == 0) ? Wa : (l == 1) ? Wb : (l == 2) ? Wc : (l == 3) ? Wd : We;
        float w = Wp[k * FEAT + col];
        _Float16 h = (_Float16)w;
        _Float16 r = (_Float16)(w - (float)h);
        w16t[gid] = h;
        wrt[gid] = r;
        if (gid < 5 * FEAT) {
            int bl = gid >> 7;
            const float* Bp = (bl == 0) ? Ba : (bl == 1) ? Bb : (bl == 2) ? Bc : (bl == 3) ? Bd : Be;
            bcat[gid] = Bp[gid & 127];
        }
    }
}

// ---------- prep2: merged scanp2+scanp3 (re-scan blockSums in LDS) + barrier init ----------
__global__ __launch_bounds__(256) void prep2_kernel(const unsigned short* __restrict__ pD,
                                                    const int* __restrict__ blockSums,
                                                    int* __restrict__ cursorV,
                                                    int* __restrict__ offsc,
                                                    int* __restrict__ barWords,
                                                    int NP, int n, int nb) {
    __shared__ int buf[256];
    int tid = threadIdx.x;
    int b = blockIdx.x;
    // scan the block sums
    int bsv = (tid < nb) ? blockSums[tid] : 0;
    buf[tid] = bsv;
    __syncthreads();
    #pragma unroll
    for (int off = 1; off < 256; off <<= 1) {
        int t = (tid >= off) ? buf[tid - off] : 0;
        __syncthreads();
        buf[tid] += t;
        __syncthreads();
    }
    int myoff = (b > 0) ? buf[b - 1] : 0;
    __syncthreads();
    // per-node slice sums + local scan
    int v = b * 256 + tid;
    int ssum = 0;
    #pragma unroll
    for (int s = 0; s < NSLICE; ++s) ssum += pD[(size_t)s * NP + v];
    buf[tid] = ssum;
    __syncthreads();
    #pragma unroll
    for (int off = 1; off < 256; off <<= 1) {
        int t = (tid >= off) ? buf[tid - off] : 0;
        __syncthreads();
        buf[tid] += t;
        __syncthreads();
    }
    int o = myoff + buf[tid] - ssum;
    if (v <= n) offsc[v] = o;          // pad nodes have zero edges -> v==n gets total
    int* cv = cursorV + (size_t)v * NSLICE;
    #pragma unroll
    for (int s = 0; s < NSLICE; ++s) {
        int val = pD[(size_t)s * NP + v];
        cv[s] = o;
        o += val;
    }
    if (b == 0 && tid < 2) barWords[tid] = 0;   // grid-barrier cnt/gen init
}

// ---------- fill: place edges via LDS cursors (XCD-swizzled slices) ----------
__global__ __launch_bounds__(1024) void fill_kernel(const int* __restrict__ src,
                                                    const int* __restrict__ dst,
                                                    const int* __restrict__ cursorV,
                                                    int* __restrict__ esrc, int E, int NP) {
    __shared__ int cur[RANGE];
    int b = blockIdx.x;
    int r = b / NSLICE;
    int inner = b % NSLICE;
    int s = ((inner & 7) << 3) | (inner >> 3);
    int v0 = r * RANGE;
    int tid = threadIdx.x;
    for (int i = tid; i < RANGE; i += 1024)
        cur[i] = cursorV[(size_t)(v0 + i) * NSLICE + s];
    __syncthreads();
    int e0 = (int)((long long)E * s / NSLICE);
    int e1 = (int)((long long)E * (s + 1) / NSLICE);
    for (int e = e0 + tid; e < e1; e += 1024) {
        unsigned dd = (unsigned)(dst[e] - v0);
        if (dd < RANGE) {
            int p = atomicAdd(&cur[dd], 1);
            esrc[p] = src[e];
        }
    }
}

// ---------- device-scope grid barrier (all blocks co-resident by construction) ----------
__device__ __forceinline__ void grid_barrier(int* cnt, int* gen, int nb) {
    __syncthreads();
    if (threadIdx.x == 0) {
        int g = __hip_atomic_load(gen, __ATOMIC_ACQUIRE, __HIP_MEMORY_SCOPE_AGENT);
        int a = __hip_atomic_fetch_add(cnt, 1, __ATOMIC_ACQ_REL, __HIP_MEMORY_SCOPE_AGENT);
        if (a == nb - 1) {
            __hip_atomic_store(cnt, 0, __ATOMIC_RELAXED, __HIP_MEMORY_SCOPE_AGENT);
            __hip_atomic_store(gen, g + 1, __ATOMIC_RELEASE, __HIP_MEMORY_SCOPE_AGENT);
        } else {
            while (__hip_atomic_load(gen, __ATOMIC_ACQUIRE, __HIP_MEMORY_SCOPE_AGENT) == g)
                __builtin_amdgcn_s_sleep(2);
        }
    }
    __syncthreads();
}

// ---------- mega: prescale + 5x (agg -> gemm) in ONE dispatch, grid barriers between phases ----
// agg: half-wave per node, fp16 gather, fp32 accumulate -> m fp32
// gemm: 64-row tile per block iter; A split f16+res in LDS (swizzled); W16/Wr direct from L2
__global__ __launch_bounds__(512, 4) void mega_kernel(const float* __restrict__ xf,
                                                      const float* __restrict__ ns,
                                                      const float* __restrict__ nd,
                                                      const int* __restrict__ offs,
                                                      const int* __restrict__ esrc,
                                                      const _Float16* __restrict__ w16t_all,
                                                      const _Float16* __restrict__ wrt_all,
                                                      const float* __restrict__ bcat,
                                                      _Float16* __restrict__ xhA,
                                                      _Float16* __restrict__ xhB,
                                                      float* __restrict__ mbuf,
                                                      float* __restrict__ outC,
                                                      int* __restrict__ barWords,
                                                      int n, int nblocks) {
    __shared__ _Float16 A16s[64 * 128];
    __shared__ _Float16 Ars[64 * 128];
    int tid = threadIdx.x;
    int bid = blockIdx.x;
    int* barCnt = barWords;
    int* barGen = barWords + 1;

    // ---- phase 0: prescale xhA = fp16(in_feat * ns) ----
    {
        int total = n * (FEAT / 8);
        for (int i = bid * 512 + tid; i < total; i += nblocks * 512) {
            int v = i >> 4;
            float w = ns[v];
            float4 t0 = ((const float4*)xf)[i * 2];
            float4 t1 = ((const float4*)xf)[i * 2 + 1];
            half8 h;
            h[0] = (_Float16)(t0.x * w); h[1] = (_Float16)(t0.y * w);
            h[2] = (_Float16)(t0.z * w); h[3] = (_Float16)(t0.w * w);
            h[4] = (_Float16)(t1.x * w); h[5] = (_Float16)(t1.y * w);
            h[6] = (_Float16)(t1.z * w); h[7] = (_Float16)(t1.w * w);
            ((float4*)xhA)[i] = __builtin_bit_cast(float4, h);
        }
    }
    grid_barrier(barCnt, barGen, nblocks);

    for (int l = 0; l < 5; ++l) {
        const _Float16* xin = (l & 1) ? xhB : xhA;
        _Float16* xout = (l & 1) ? xhA : xhB;
        const _Float16* w16t = w16t_all + (size_t)l * 16384;
        const _Float16* wrt  = wrt_all + (size_t)l * 16384;
        const float* bias = bcat + l * FEAT;

        // ---- agg phase: m[v] = nd[v] * sum_{e in N(v)} xin[esrc[e]] ----
        {
            int lane = tid & 31;
            int q = lane >> 4;           // edge stream 0/1
            int c = lane & 15;           // 16 lanes x 16B cover a 128-half row
            int hw0 = (bid * 512 + tid) >> 5;
            int nhw = nblocks * 16;
            for (int v = hw0; v < n; v += nhw) {
                int s0 = offs[v], s1 = offs[v + 1];
                float a0[8] = {0,0,0,0,0,0,0,0};
                float a1[8] = {0,0,0,0,0,0,0,0};
                float a2[8] = {0,0,0,0,0,0,0,0};
                float a3[8] = {0,0,0,0,0,0,0,0};
                int j = s0 + q;
                for (; j + 6 < s1; j += 8) {
                    int e0 = esrc[j], e1 = esrc[j + 2], e2 = esrc[j + 4], e3 = esrc[j + 6];
                    float4 r0v = ((const float4*)(xin + (size_t)e0 * FEAT))[c];
                    float4 r1v = ((const float4*)(xin + (size_t)e1 * FEAT))[c];
                    float4 r2v = ((const float4*)(xin + (size_t)e2 * FEAT))[c];
                    float4 r3v = ((const float4*)(xin + (size_t)e3 * FEAT))[c];
                    half8 h0 = __builtin_bit_cast(half8, r0v);
                    half8 h1 = __builtin_bit_cast(half8, r1v);
                    half8 h2 = __builtin_bit_cast(half8, r2v);
                    half8 h3 = __builtin_bit_cast(half8, r3v);
                    #pragma unroll
                    for (int k = 0; k < 8; ++k) {
                        a0[k] += (float)h0[k];
                        a1[k] += (float)h1[k];
                        a2[k] += (float)h2[k];
                        a3[k] += (float)h3[k];
                    }
                }
                for (; j < s1; j += 2) {
                    int e0 = esrc[j];
                    float4 r0v = ((const float4*)(xin + (size_t)e0 * FEAT))[c];
                    half8 h0 = __builtin_bit_cast(half8, r0v);
                    #pragma unroll
                    for (int k = 0; k < 8; ++k) a0[k] += (float)h0[k];
                }
                float r[8];
                #pragma unroll
                for (int k = 0; k < 8; ++k) r[k] = (a0[k] + a1[k]) + (a2[k] + a3[k]);
                #pragma unroll
                for (int k = 0; k < 8; ++k) r[k] += __shfl_xor(r[k], 16);   // cross-stream
                if (q == 0) {
                    float sc = nd[v];
                    float4 o0, o1;
                    o0.x = r[0] * sc; o0.y = r[1] * sc; o0.z = r[2] * sc; o0.w = r[3] * sc;
                    o1.x = r[4] * sc; o1.y = r[5] * sc; o1.z = r[6] * sc; o1.w = r[7] * sc;
                    ((float4*)(mbuf + (size_t)v * FEAT))[c * 2] = o0;
                    ((float4*)(mbuf + (size_t)v * FEAT))[c * 2 + 1] = o1;
                }
            }
        }
        grid_barrier(barCnt, barGen, nblocks);

        // ---- gemm phase: h = relu(m @ W + b); l<4: *ns -> fp16; l==4: fp32 + threshold ----
        {
            int lane64 = tid & 63;
            int w = tid >> 6;              // 8 waves: 4 row-groups x 2 col-groups
            int l15 = lane64 & 15;
            int qq = lane64 >> 4;
            int rw = w & 3, cw = w >> 2;
            int rbase = rw * 16 + l15;
            int cbase = cw * 64;
            int ntiles = (n + 63) / 64;
            for (int tile = bid; tile < ntiles; tile += nblocks) {
                int r0 = tile * 64;
                __syncthreads();           // protect LDS reuse across tile iterations
                #pragma unroll
                for (int jj = 0; jj < 4; ++jj) {
                    int i = tid + jj * 512;          // 2048 float4 of source fp32
                    int row = i >> 5, c4 = i & 31;
                    int gr = r0 + row;
                    float4 v = make_float4(0.f, 0.f, 0.f, 0.f);
                    if (gr < n) v = ((const float4*)(mbuf + (size_t)gr * FEAT))[c4];
                    _Float16 h0 = (_Float16)v.x, h1 = (_Float16)v.y;
                    _Float16 h2 = (_Float16)v.z, h3 = (_Float16)v.w;
                    int d = row * 128 + (((c4 >> 1) ^ (row & 7)) << 3) + ((c4 & 1) << 2);
                    A16s[d + 0] = h0; A16s[d + 1] = h1; A16s[d + 2] = h2; A16s[d + 3] = h3;
                    Ars[d + 0] = (_Float16)(v.x - (float)h0);
                    Ars[d + 1] = (_Float16)(v.y - (float)h1);
                    Ars[d + 2] = (_Float16)(v.z - (float)h2);
                    Ars[d + 3] = (_Float16)(v.w - (float)h3);
                }
                __syncthreads();
                f32x4 acc[4] = {{0.f,0.f,0.f,0.f},{0.f,0.f,0.f,0.f},
                                {0.f,0.f,0.f,0.f},{0.f,0.f,0.f,0.f}};
                #pragma unroll
                for (int ks = 0; ks < 4; ++ks) {
                    int chunk = ks * 4 + qq;
                    int aoff = rbase * 128 + ((chunk ^ (rbase & 7)) << 3);
                    half8 a16 = *(const half8*)(A16s + aoff);
                    half8 ar  = *(const half8*)(Ars + aoff);
                    #pragma unroll
                    for (int ct = 0; ct < 4; ++ct) {
                        int col = cbase + ct * 16 + l15;
                        half8 b16 = *(const half8*)(w16t + (size_t)col * FEAT + chunk * 8);
                        half8 br  = *(const half8*)(wrt  + (size_t)col * FEAT + chunk * 8);
                        acc[ct] = __builtin_amdgcn_mfma_f32_16x16x32_f16(a16, b16, acc[ct], 0, 0, 0);
                        acc[ct] = __builtin_amdgcn_mfma_f32_16x16x32_f16(a16, br,  acc[ct], 0, 0, 0);
                        acc[ct] = __builtin_amdgcn_mfma_f32_16x16x32_f16(ar,  b16, acc[ct], 0, 0, 0);
                    }
                }
                // epilogue: C/D layout col=lane&15, row=(lane>>4)*4+reg
                int rloc = rw * 16 + qq * 4;
                float scv[4];
                #pragma unroll
                for (int reg = 0; reg < 4; ++reg) {
                    int row = r0 + rloc + reg;
                    scv[reg] = (l < 4 && row < n) ? ns[row] : 1.0f;
                }
                #pragma unroll
                for (int ct = 0; ct < 4; ++ct) {
                    int col = cbase + ct * 16 + l15;
                    float b = bias[col];
                    #pragma unroll
                    for (int reg = 0; reg < 4; ++reg) {
                        int row = r0 + rloc + reg;
                        if (row < n) {
                            float h = acc[ct][reg] + b;
                            h = h > 0.f ? h : 0.f;
                            if (l < 4) {
                                xout[(size_t)row * FEAT + col] = (_Float16)(h * scv[reg]);
                            } else {
                                mbuf[(size_t)row * FEAT + col] = h;
                                outC[(size_t)row * FEAT + col] = h >= 0.5f ? 1.f : 0.f;
                            }
                        }
                    }
                }
            }
        }
        if (l < 4) grid_barrier(barCnt, barGen, nblocks);
    }
}

extern "C" void kernel_launch(void* const* d_in, const int* in_sizes, int n_in,
                              void* d_out, int out_size, void* d_ws, size_t ws_size,
                              hipStream_t stream) {
    const float* in_feat = (const float*)d_in[0];
    const int*   src     = (const int*)d_in[1];
    const int*   dst     = (const int*)d_in[2];
    const float* W[5] = {(const float*)d_in[3], (const float*)d_in[5], (const float*)d_in[7],
                         (const float*)d_in[9], (const float*)d_in[11]};
    const float* B[5] = {(const float*)d_in[4], (const float*)d_in[6], (const float*)d_in[8],
                         (const float*)d_in[10], (const float*)d_in[12]};
    const int E = in_sizes[1];
    const int N = in_sizes[0] / FEAT;
    const int NRANGE = (N + RANGE - 1) / RANGE;       // 4
    const int NP = NRANGE * RANGE;                    // 51200
    const size_t MTOT = (size_t)NP * NSLICE;          // 3,276,800

    char* ws = (char*)d_ws;
    size_t off = 0;
    auto alloc = [&](size_t bytes) { size_t o = off; off += (bytes + 255) & ~size_t(255); return o; };
    unsigned* partialD = (unsigned*)(ws + alloc(MTOT * 2));
    size_t    pS_off   = alloc(MTOT * 2);
    unsigned* partialS = (unsigned*)(ws + pS_off);
    int*      esrc     = (int*)(ws + pS_off);          // aliases partialS (dead after prep1)
    size_t    cV_off   = alloc(MTOT * 4);
    int*      cursorV  = (int*)(ws + cV_off);
    _Float16* xhA      = (_Float16*)(ws + cV_off);     // aliases cursorV (dead after fill)
    float*    ns       = (float*)(ws + alloc((size_t)N * 4));
    float*    nd       = (float*)(ws + alloc((size_t)N * 4));
    int*      offsc    = (int*)(ws + alloc((size_t)(N + 1) * 4));
    int*      blockSums = (int*)(ws + alloc(1024));
    int*      barWords = (int*)(ws + alloc(256));
    _Float16* w16t     = (_Float16*)(ws + alloc(5 * 16384 * 2));
    _Float16* wrt      = (_Float16*)(ws + alloc(5 * 16384 * 2));
    float*    bcat     = (float*)(ws + alloc(5 * FEAT * 4));
    _Float16* xhB      = (_Float16*)(ws + alloc((size_t)N * FEAT * 2));

    float* out_h = (float*)d_out;                     // m scratch during layers; final h
    float* out_c = out_h + (size_t)N * FEAT;          // threshold output

    const int histBlocks = 2 * NRANGE * NSLICE;       // 512
    const int scanBlocks = NP / 256;                  // 200
    const int MEGA_BLOCKS = 448;                      // 512t, 32KB LDS, <=128 VGPR -> 2/CU co-resident

    hist_kernel<<<histBlocks, 1024, 0, stream>>>(src, dst, partialD, partialS, E, NP);
    prep1_kernel<<<scanBlocks + 320, 256, 0, stream>>>((const unsigned short*)partialD,
                                                       (const unsigned short*)partialS,
                                                       blockSums, ns, nd,
                                                       W[0], W[1], W[2], W[3], W[4],
                                                       B[0], B[1], B[2], B[3], B[4],
                                                       w16t, wrt, bcat, NP, N, scanBlocks);
    prep2_kernel<<<scanBlocks, 256, 0, stream>>>((const unsigned short*)partialD, blockSums,
                                                 cursorV, offsc, barWords, NP, N, scanBlocks);
    fill_kernel<<<NRANGE * NSLICE, 1024, 0, stream>>>(src, dst, cursorV, esrc, E, NP);
    mega_kernel<<<MEGA_BLOCKS, 512, 0, stream>>>(in_feat, ns, nd, offsc, esrc,
                                                 w16t, wrt, bcat, xhA, xhB,
                                                 out_h, out_c, barWords, N, MEGA_BLOCKS);
}

// Round 7
// 530.232 us; speedup vs baseline: 2.6726x; 2.6726x over previous
//
#include <hip/hip_runtime.h>

#define FEAT 128
#define RANGE 12800
#define NSLICE 64

typedef _Float16 half8 __attribute__((ext_vector_type(8)));
typedef _Float16 half4v __attribute__((ext_vector_type(4)));
typedef float f32x4 __attribute__((ext_vector_type(4)));

// ---------- hist: src & dst partial histograms in one dispatch, ushort-packed ----------
__global__ __launch_bounds__(1024) void hist_kernel(const int* __restrict__ src,
                                                    const int* __restrict__ dst,
                                                    unsigned* __restrict__ partialD,
                                                    unsigned* __restrict__ partialS,
                                                    int E, int NP) {
    __shared__ unsigned hpk[RANGE / 2];
    int per = (NP / RANGE) * NSLICE;
    int b = blockIdx.x;
    int halfsel = b / per;           // 0 = dst histogram, 1 = src histogram
    int q = b % per;
    int r = q / NSLICE;
    int s = q % NSLICE;
    const int* arr = halfsel ? src : dst;
    unsigned* out = halfsel ? partialS : partialD;
    int v0 = r * RANGE;
    int tid = threadIdx.x;
    for (int i = tid; i < RANGE / 2; i += 1024) hpk[i] = 0;
    __syncthreads();
    int e0 = (int)((long long)E * s / NSLICE);
    int e1 = (int)((long long)E * (s + 1) / NSLICE);
    for (int e = e0 + tid; e < e1; e += 1024) {
        unsigned d = (unsigned)(arr[e] - v0);
        if (d < RANGE) atomicAdd(&hpk[d >> 1], (d & 1) ? 65536u : 1u);
    }
    __syncthreads();
    size_t wbase = ((size_t)s * NP + v0) >> 1;
    for (int i = tid; i < RANGE / 2; i += 1024) out[wbase + i] = hpk[i];
}

// ---------- prep1: blocks [0,sb): scanp1 (slice sums + norms + blockSums)
//                   blocks [sb, sb+320): W fp16 value+residual transpose ----------
__global__ __launch_bounds__(256) void prep1_kernel(const unsigned short* __restrict__ pD,
                                                    const unsigned short* __restrict__ pS,
                                                    int* __restrict__ blockSums,
                                                    float* __restrict__ ns,
                                                    float* __restrict__ nd,
                                                    const float* __restrict__ Wa,
                                                    const float* __restrict__ Wb,
                                                    const float* __restrict__ Wc,
                                                    const float* __restrict__ Wd,
                                                    const float* __restrict__ We,
                                                    _Float16* __restrict__ w16t,
                                                    _Float16* __restrict__ wrt,
                                                    int NP, int n, int sb) {
    int tid = threadIdx.x;
    int b = blockIdx.x;
    if (b < sb) {
        __shared__ int buf[256];
        int v = b * 256 + tid;
        int ssum = 0, osum = 0;
        #pragma unroll
        for (int s = 0; s < NSLICE; ++s) {
            ssum += pD[(size_t)s * NP + v];
            osum += pS[(size_t)s * NP + v];
        }
        if (v < n) {
            ns[v] = 1.0f / sqrtf((float)(osum < 1 ? 1 : osum));
            nd[v] = 1.0f / sqrtf((float)(ssum < 1 ? 1 : ssum));
        }
        buf[tid] = ssum;
        __syncthreads();
        #pragma unroll
        for (int off = 1; off < 256; off <<= 1) {
            int t = (tid >= off) ? buf[tid - off] : 0;
            __syncthreads();
            buf[tid] += t;
            __syncthreads();
        }
        if (tid == 255) blockSums[b] = buf[255];
    } else {
        int gid = (b - sb) * 256 + tid;              // 0 .. 81919
        int l = gid >> 14;
        int idx = gid & 16383;
        int col = idx >> 7;
        int k = idx & 127;
        const float* Wp = (l == 0) ? Wa : (l == 1) ? Wb : (l == 2) ? Wc : (l == 3) ? Wd : We;
        float w = Wp[k * FEAT + col];
        _Float16 h = (_Float16)w;
        _Float16 r = (_Float16)(w - (float)h);
        w16t[gid] = h;
        wrt[gid] = r;
    }
}

// ---------- prep2: merged scanp2+scanp3 (re-scan blockSums in LDS per block) ----------
__global__ __launch_bounds__(256) void prep2_kernel(const unsigned short* __restrict__ pD,
                                                    const int* __restrict__ blockSums,
                                                    int* __restrict__ cursorV,
                                                    int* __restrict__ offsc,
                                                    int NP, int n, int nb) {
    __shared__ int buf[256];
    int tid = threadIdx.x;
    int b = blockIdx.x;
    // scan the block sums (all blocks redo this tiny scan)
    int bsv = (tid < nb) ? blockSums[tid] : 0;
    buf[tid] = bsv;
    __syncthreads();
    #pragma unroll
    for (int off = 1; off < 256; off <<= 1) {
        int t = (tid >= off) ? buf[tid - off] : 0;
        __syncthreads();
        buf[tid] += t;
        __syncthreads();
    }
    int myoff = (b > 0) ? buf[b - 1] : 0;
    __syncthreads();
    // per-node slice sums + local scan
    int v = b * 256 + tid;
    int ssum = 0;
    #pragma unroll
    for (int s = 0; s < NSLICE; ++s) ssum += pD[(size_t)s * NP + v];
    buf[tid] = ssum;
    __syncthreads();
    #pragma unroll
    for (int off = 1; off < 256; off <<= 1) {
        int t = (tid >= off) ? buf[tid - off] : 0;
        __syncthreads();
        buf[tid] += t;
        __syncthreads();
    }
    int o = myoff + buf[tid] - ssum;
    if (v <= n) offsc[v] = o;          // pad nodes have zero edges -> v==n gets total
    int* cv = cursorV + (size_t)v * NSLICE;
    #pragma unroll
    for (int s = 0; s < NSLICE; ++s) {
        int val = pD[(size_t)s * NP + v];
        cv[s] = o;
        o += val;
    }
}

// ---------- fill: place edges via LDS cursors (XCD-swizzled slices) ----------
__global__ __launch_bounds__(1024) void fill_kernel(const int* __restrict__ src,
                                                    const int* __restrict__ dst,
                                                    const int* __restrict__ cursorV,
                                                    int* __restrict__ esrc, int E, int NP) {
    __shared__ int cur[RANGE];
    int b = blockIdx.x;
    int r = b / NSLICE;
    int inner = b % NSLICE;
    int s = ((inner & 7) << 3) | (inner >> 3);
    int v0 = r * RANGE;
    int tid = threadIdx.x;
    for (int i = tid; i < RANGE; i += 1024)
        cur[i] = cursorV[(size_t)(v0 + i) * NSLICE + s];
    __syncthreads();
    int e0 = (int)((long long)E * s / NSLICE);
    int e1 = (int)((long long)E * (s + 1) / NSLICE);
    for (int e = e0 + tid; e < e1; e += 1024) {
        unsigned dd = (unsigned)(dst[e] - v0);
        if (dd < RANGE) {
            int p = atomicAdd(&cur[dd], 1);
            esrc[p] = src[e];
        }
    }
}

// ---------- prescale: xh = fp16(in_feat * ns) ----------
__global__ void prescale_kernel(const float* __restrict__ x, const float* __restrict__ ns,
                                _Float16* __restrict__ xh, int n) {
    int i = blockIdx.x * blockDim.x + threadIdx.x;   // one thread per 8 elements
    if (i >= n * (FEAT / 8)) return;
    int v = i >> 4;
    float w = ns[v];
    float4 t0 = ((const float4*)x)[i * 2];
    float4 t1 = ((const float4*)x)[i * 2 + 1];
    half8 h;
    h[0] = (_Float16)(t0.x * w); h[1] = (_Float16)(t0.y * w);
    h[2] = (_Float16)(t0.z * w); h[3] = (_Float16)(t0.w * w);
    h[4] = (_Float16)(t1.x * w); h[5] = (_Float16)(t1.y * w);
    h[6] = (_Float16)(t1.z * w); h[7] = (_Float16)(t1.w * w);
    ((float4*)xh)[i] = __builtin_bit_cast(float4, h);
}

// ---------- aggregation: fp16 gather (256 B/row), fp32 accumulate (round-3 proven) ----------
__global__ __launch_bounds__(256) void agg_kernel(const _Float16* __restrict__ x,
                                                  const int* __restrict__ offs,
                                                  const int* __restrict__ esrc,
                                                  const float* __restrict__ nd,
                                                  float* __restrict__ m, int n) {
    int gid = blockIdx.x * blockDim.x + threadIdx.x;
    int v = gid >> 6;
    if (v >= n) return;
    int lane = threadIdx.x & 63;
    int q = lane >> 4;       // quarter 0..3: independent edge stream, stride 4
    int c = lane & 15;       // 16 lanes x 16B cover a 128-half row; lane c = cols 8c..8c+7
    int s0 = offs[v], s1 = offs[v + 1];
    float a0[8] = {0,0,0,0,0,0,0,0};
    float a1[8] = {0,0,0,0,0,0,0,0};
    float a2[8] = {0,0,0,0,0,0,0,0};
    float a3[8] = {0,0,0,0,0,0,0,0};
    int j = s0 + q;
    for (; j + 12 < s1; j += 16) {
        int e0 = esrc[j], e1 = esrc[j + 4], e2 = esrc[j + 8], e3 = esrc[j + 12];
        float4 r0 = ((const float4*)(x + (size_t)e0 * FEAT))[c];
        float4 r1 = ((const float4*)(x + (size_t)e1 * FEAT))[c];
        float4 r2 = ((const float4*)(x + (size_t)e2 * FEAT))[c];
        float4 r3 = ((const float4*)(x + (size_t)e3 * FEAT))[c];
        half8 h0 = __builtin_bit_cast(half8, r0);
        half8 h1 = __builtin_bit_cast(half8, r1);
        half8 h2 = __builtin_bit_cast(half8, r2);
        half8 h3 = __builtin_bit_cast(half8, r3);
        #pragma unroll
        for (int k = 0; k < 8; ++k) {
            a0[k] += (float)h0[k];
            a1[k] += (float)h1[k];
            a2[k] += (float)h2[k];
            a3[k] += (float)h3[k];
        }
    }
    for (; j < s1; j += 4) {
        int e0 = esrc[j];
        float4 r0 = ((const float4*)(x + (size_t)e0 * FEAT))[c];
        half8 h0 = __builtin_bit_cast(half8, r0);
        #pragma unroll
        for (int k = 0; k < 8; ++k) a0[k] += (float)h0[k];
    }
    float r[8];
    #pragma unroll
    for (int k = 0; k < 8; ++k) r[k] = (a0[k] + a1[k]) + (a2[k] + a3[k]);
    #pragma unroll
    for (int k = 0; k < 8; ++k) {
        r[k] += __shfl_xor(r[k], 16);
        r[k] += __shfl_xor(r[k], 32);
    }
    if (lane < 16) {
        float sc = nd[v];
        float4 o0, o1;
        o0.x = r[0] * sc; o0.y = r[1] * sc; o0.z = r[2] * sc; o0.w = r[3] * sc;
        o1.x = r[4] * sc; o1.y = r[5] * sc; o1.z = r[6] * sc; o1.w = r[7] * sc;
        ((float4*)(m + (size_t)v * FEAT))[c * 2] = o0;
        ((float4*)(m + (size_t)v * FEAT))[c * 2 + 1] = o1;
    }
}

// ---------- GEMM: MFMA f16 value+residual; A-only LDS; W16/Wr direct from L2 ----------
// 64x128 tile, 512 threads (8 waves: 4 row x 2 col), 32KB LDS.
// acc = A16*W16 + A16*Wr + Ar*W16  (drops Ar*Wr ~ 2.4e-7 rel)
template<int MODE>   // 0: relu*ns -> fp16   1: last layer (fp32 h + threshold)
__global__ __launch_bounds__(512, 4) void gemm_kernel(const float* __restrict__ M,
                                                      const _Float16* __restrict__ w16t,
                                                      const _Float16* __restrict__ wrt,
                                                      const float* __restrict__ bias,
                                                      const float* __restrict__ nsv,
                                                      _Float16* __restrict__ outh,
                                                      float* __restrict__ outf,
                                                      float* __restrict__ out2, int n) {
    __shared__ _Float16 A16s[64 * 128];
    __shared__ _Float16 Ars[64 * 128];
    int tid = threadIdx.x;
    int r0 = blockIdx.x * 64;

    // stage A rows r0..r0+63: fp32 -> fp16 value + residual, XOR-swizzled
    #pragma unroll
    for (int jj = 0; jj < 4; ++jj) {
        int i = tid + jj * 512;            // 2048 float4 of source fp32
        int row = i >> 5, c4 = i & 31;
        int gr = r0 + row;
        float4 v = make_float4(0.f, 0.f, 0.f, 0.f);
        if (gr < n) v = ((const float4*)(M + (size_t)gr * FEAT))[c4];
        half4v h, rr;
        h[0] = (_Float16)v.x; h[1] = (_Float16)v.y; h[2] = (_Float16)v.z; h[3] = (_Float16)v.w;
        rr[0] = (_Float16)(v.x - (float)h[0]); rr[1] = (_Float16)(v.y - (float)h[1]);
        rr[2] = (_Float16)(v.z - (float)h[2]); rr[3] = (_Float16)(v.w - (float)h[3]);
        int d = row * 128 + (((c4 >> 1) ^ (row & 7)) << 3) + ((c4 & 1) << 2);
        *(half4v*)(A16s + d) = h;
        *(half4v*)(Ars + d) = rr;
    }
    __syncthreads();

    int lane64 = tid & 63;
    int w = tid >> 6;                      // 8 waves: 4 row-groups x 2 col-groups
    int l15 = lane64 & 15;
    int qq = lane64 >> 4;
    int rw = w & 3, cw = w >> 2;
    int rbase = rw * 16 + l15;
    int cbase = cw * 64;

    f32x4 acc[4] = {{0.f,0.f,0.f,0.f},{0.f,0.f,0.f,0.f},{0.f,0.f,0.f,0.f},{0.f,0.f,0.f,0.f}};
    #pragma unroll
    for (int ks = 0; ks < 4; ++ks) {
        int chunk = ks * 4 + qq;
        int aoff = rbase * 128 + ((chunk ^ (rbase & 7)) << 3);
        half8 a16 = *(const half8*)(A16s + aoff);
        half8 ar  = *(const half8*)(Ars + aoff);
        #pragma unroll
        for (int ct = 0; ct < 4; ++ct) {
            int col = cbase + ct * 16 + l15;
            half8 b16 = *(const half8*)(w16t + (size_t)col * FEAT + chunk * 8);
            half8 br  = *(const half8*)(wrt  + (size_t)col * FEAT + chunk * 8);
            acc[ct] = __builtin_amdgcn_mfma_f32_16x16x32_f16(a16, b16, acc[ct], 0, 0, 0);
            acc[ct] = __builtin_amdgcn_mfma_f32_16x16x32_f16(a16, br,  acc[ct], 0, 0, 0);
            acc[ct] = __builtin_amdgcn_mfma_f32_16x16x32_f16(ar,  b16, acc[ct], 0, 0, 0);
        }
    }

    // epilogue: C/D layout col=lane&15, row=(lane>>4)*4+reg
    int rloc = rw * 16 + qq * 4;
    float scv[4];
    #pragma unroll
    for (int reg = 0; reg < 4; ++reg) {
        int row = r0 + rloc + reg;
        scv[reg] = (MODE == 0 && row < n) ? nsv[row] : 1.0f;
    }
    #pragma unroll
    for (int ct = 0; ct < 4; ++ct) {
        int col = cbase + ct * 16 + l15;
        float b = bias[col];
        #pragma unroll
        for (int reg = 0; reg < 4; ++reg) {
            int row = r0 + rloc + reg;
            if (row < n) {
                float h = acc[ct][reg] + b;
                h = h > 0.f ? h : 0.f;
                if (MODE == 0) {
                    outh[(size_t)row * FEAT + col] = (_Float16)(h * scv[reg]);
                } else {
                    outf[(size_t)row * FEAT + col] = h;
                    out2[(size_t)row * FEAT + col] = h >= 0.5f ? 1.f : 0.f;
                }
            }
        }
    }
}

extern "C" void kernel_launch(void* const* d_in, const int* in_sizes, int n_in,
                              void* d_out, int out_size, void* d_ws, size_t ws_size,
                              hipStream_t stream) {
    const float* in_feat = (const float*)d_in[0];
    const int*   src     = (const int*)d_in[1];
    const int*   dst     = (const int*)d_in[2];
    const float* W[5] = {(const float*)d_in[3], (const float*)d_in[5], (const float*)d_in[7],
                         (const float*)d_in[9], (const float*)d_in[11]};
    const float* B[5] = {(const float*)d_in[4], (const float*)d_in[6], (const float*)d_in[8],
                         (const float*)d_in[10], (const float*)d_in[12]};
    const int E = in_sizes[1];
    const int N = in_sizes[0] / FEAT;
    const int NRANGE = (N + RANGE - 1) / RANGE;       // 4
    const int NP = NRANGE * RANGE;                    // 51200
    const size_t MTOT = (size_t)NP * NSLICE;          // 3,276,800

    char* ws = (char*)d_ws;
    size_t off = 0;
    auto alloc = [&](size_t bytes) { size_t o = off; off += (bytes + 255) & ~size_t(255); return o; };
    unsigned* partialD = (unsigned*)(ws + alloc(MTOT * 2));
    size_t    pS_off   = alloc(MTOT * 2);
    unsigned* partialS = (unsigned*)(ws + pS_off);
    int*      esrc     = (int*)(ws + pS_off);          // aliases partialS (dead after prep1)
    size_t    cV_off   = alloc(MTOT * 4);
    int*      cursorV  = (int*)(ws + cV_off);
    _Float16* xh       = (_Float16*)(ws + cV_off);     // aliases cursorV (dead after fill); 12.8MB <= 13.1MB
    float*    ns       = (float*)(ws + alloc((size_t)N * 4));
    float*    nd       = (float*)(ws + alloc((size_t)N * 4));
    int*      offsc    = (int*)(ws + alloc((size_t)(N + 1) * 4));
    int*      blockSums = (int*)(ws + alloc(1024));
    _Float16* w16t     = (_Float16*)(ws + alloc(5 * 16384 * 2));
    _Float16* wrt      = (_Float16*)(ws + alloc(5 * 16384 * 2));

    float* out_h = (float*)d_out;                     // m scratch; final h
    float* out_c = out_h + (size_t)N * FEAT;          // threshold output

    const int histBlocks = 2 * NRANGE * NSLICE;       // 512
    const int scanBlocks = NP / 256;                  // 200

    hist_kernel<<<histBlocks, 1024, 0, stream>>>(src, dst, partialD, partialS, E, NP);
    prep1_kernel<<<scanBlocks + 320, 256, 0, stream>>>((const unsigned short*)partialD,
                                                       (const unsigned short*)partialS,
                                                       blockSums, ns, nd,
                                                       W[0], W[1], W[2], W[3], W[4],
                                                       w16t, wrt, NP, N, scanBlocks);
    prep2_kernel<<<scanBlocks, 256, 0, stream>>>((const unsigned short*)partialD, blockSums,
                                                 cursorV, offsc, NP, N, scanBlocks);
    fill_kernel<<<NRANGE * NSLICE, 1024, 0, stream>>>(src, dst, cursorV, esrc, E, NP);
    // prescale AFTER fill: xh aliases cursorV
    prescale_kernel<<<(N * (FEAT / 8) + 255) / 256, 256, 0, stream>>>(in_feat, ns, xh, N);

    const int agg_blocks = (int)(((size_t)N * 64 + 255) / 256);   // 12500
    const int gemm_blocks = (N + 63) / 64;                        // 782

    for (int l = 0; l < 5; ++l) {
        agg_kernel<<<agg_blocks, 256, 0, stream>>>(xh, offsc, esrc, nd, out_h, N);
        if (l < 4)
            gemm_kernel<0><<<gemm_blocks, 512, 0, stream>>>(out_h, w16t + (size_t)l * 16384,
                                                            wrt + (size_t)l * 16384, B[l], ns,
                                                            xh, nullptr, nullptr, N);
        else
            gemm_kernel<1><<<gemm_blocks, 512, 0, stream>>>(out_h, w16t + (size_t)l * 16384,
                                                            wrt + (size_t)l * 16384, B[l], nullptr,
                                                            nullptr, out_h, out_c, N);
    }
}

// Round 8
// 433.812 us; speedup vs baseline: 3.2666x; 1.2223x over previous
//
#include <hip/hip_runtime.h>

#define FEAT 128
#define RANGE 12800
#define NSLICE 64

typedef _Float16 half8 __attribute__((ext_vector_type(8)));
typedef _Float16 half4v __attribute__((ext_vector_type(4)));
typedef float f32x4 __attribute__((ext_vector_type(4)));

// ---------- hist: src & dst partial histograms in one dispatch, ushort-packed ----------
__global__ __launch_bounds__(1024) void hist_kernel(const int* __restrict__ src,
                                                    const int* __restrict__ dst,
                                                    unsigned* __restrict__ partialD,
                                                    unsigned* __restrict__ partialS,
                                                    int E, int NP) {
    __shared__ unsigned hpk[RANGE / 2];
    int per = (NP / RANGE) * NSLICE;
    int b = blockIdx.x;
    int halfsel = b / per;           // 0 = dst histogram, 1 = src histogram
    int q = b % per;
    int r = q / NSLICE;
    int s = q % NSLICE;
    const int* arr = halfsel ? src : dst;
    unsigned* out = halfsel ? partialS : partialD;
    int v0 = r * RANGE;
    int tid = threadIdx.x;
    for (int i = tid; i < RANGE / 2; i += 1024) hpk[i] = 0;
    __syncthreads();
    int e0 = (int)((long long)E * s / NSLICE);
    int e1 = (int)((long long)E * (s + 1) / NSLICE);
    for (int e = e0 + tid; e < e1; e += 1024) {
        unsigned d = (unsigned)(arr[e] - v0);
        if (d < RANGE) atomicAdd(&hpk[d >> 1], (d & 1) ? 65536u : 1u);
    }
    __syncthreads();
    size_t wbase = ((size_t)s * NP + v0) >> 1;
    for (int i = tid; i < RANGE / 2; i += 1024) out[wbase + i] = hpk[i];
}

// ---------- prep1: blocks [0,sb): scanp1 (slice sums + norms + blockSums)
//                   blocks [sb, sb+320): W fp16 value+residual transpose ----------
__global__ __launch_bounds__(256) void prep1_kernel(const unsigned short* __restrict__ pD,
                                                    const unsigned short* __restrict__ pS,
                                                    int* __restrict__ blockSums,
                                                    float* __restrict__ ns,
                                                    float* __restrict__ nd,
                                                    const float* __restrict__ Wa,
                                                    const float* __restrict__ Wb,
                                                    const float* __restrict__ Wc,
                                                    const float* __restrict__ Wd,
                                                    const float* __restrict__ We,
                                                    _Float16* __restrict__ w16t,
                                                    _Float16* __restrict__ wrt,
                                                    int NP, int n, int sb) {
    int tid = threadIdx.x;
    int b = blockIdx.x;
    if (b < sb) {
        __shared__ int buf[256];
        int v = b * 256 + tid;
        int ssum = 0, osum = 0;
        #pragma unroll
        for (int s = 0; s < NSLICE; ++s) {
            ssum += pD[(size_t)s * NP + v];
            osum += pS[(size_t)s * NP + v];
        }
        if (v < n) {
            ns[v] = 1.0f / sqrtf((float)(osum < 1 ? 1 : osum));
            nd[v] = 1.0f / sqrtf((float)(ssum < 1 ? 1 : ssum));
        }
        buf[tid] = ssum;
        __syncthreads();
        #pragma unroll
        for (int off = 1; off < 256; off <<= 1) {
            int t = (tid >= off) ? buf[tid - off] : 0;
            __syncthreads();
            buf[tid] += t;
            __syncthreads();
        }
        if (tid == 255) blockSums[b] = buf[255];
    } else {
        int gid = (b - sb) * 256 + tid;              // 0 .. 81919
        int l = gid >> 14;
        int idx = gid & 16383;
        int col = idx >> 7;
        int k = idx & 127;
        const float* Wp = (l == 0) ? Wa : (l == 1) ? Wb : (l == 2) ? Wc : (l == 3) ? Wd : We;
        float w = Wp[k * FEAT + col];
        _Float16 h = (_Float16)w;
        _Float16 r = (_Float16)(w - (float)h);
        w16t[gid] = h;
        wrt[gid] = r;
    }
}

// ---------- prep2: merged scanp2+scanp3 (re-scan blockSums in LDS per block) ----------
__global__ __launch_bounds__(256) void prep2_kernel(const unsigned short* __restrict__ pD,
                                                    const int* __restrict__ blockSums,
                                                    int* __restrict__ cursorV,
                                                    int* __restrict__ offsc,
                                                    int NP, int n, int nb) {
    __shared__ int buf[256];
    int tid = threadIdx.x;
    int b = blockIdx.x;
    int bsv = (tid < nb) ? blockSums[tid] : 0;
    buf[tid] = bsv;
    __syncthreads();
    #pragma unroll
    for (int off = 1; off < 256; off <<= 1) {
        int t = (tid >= off) ? buf[tid - off] : 0;
        __syncthreads();
        buf[tid] += t;
        __syncthreads();
    }
    int myoff = (b > 0) ? buf[b - 1] : 0;
    __syncthreads();
    int v = b * 256 + tid;
    int ssum = 0;
    #pragma unroll
    for (int s = 0; s < NSLICE; ++s) ssum += pD[(size_t)s * NP + v];
    buf[tid] = ssum;
    __syncthreads();
    #pragma unroll
    for (int off = 1; off < 256; off <<= 1) {
        int t = (tid >= off) ? buf[tid - off] : 0;
        __syncthreads();
        buf[tid] += t;
        __syncthreads();
    }
    int o = myoff + buf[tid] - ssum;
    if (v <= n) offsc[v] = o;          // pad nodes have zero edges -> v==n gets total
    int* cv = cursorV + (size_t)v * NSLICE;
    #pragma unroll
    for (int s = 0; s < NSLICE; ++s) {
        int val = pD[(size_t)s * NP + v];
        cv[s] = o;
        o += val;
    }
}

// ---------- fill: place edges via LDS cursors (XCD-swizzled slices) ----------
__global__ __launch_bounds__(1024) void fill_kernel(const int* __restrict__ src,
                                                    const int* __restrict__ dst,
                                                    const int* __restrict__ cursorV,
                                                    int* __restrict__ esrc, int E, int NP) {
    __shared__ int cur[RANGE];
    int b = blockIdx.x;
    int r = b / NSLICE;
    int inner = b % NSLICE;
    int s = ((inner & 7) << 3) | (inner >> 3);
    int v0 = r * RANGE;
    int tid = threadIdx.x;
    for (int i = tid; i < RANGE; i += 1024)
        cur[i] = cursorV[(size_t)(v0 + i) * NSLICE + s];
    __syncthreads();
    int e0 = (int)((long long)E * s / NSLICE);
    int e1 = (int)((long long)E * (s + 1) / NSLICE);
    for (int e = e0 + tid; e < e1; e += 1024) {
        unsigned dd = (unsigned)(dst[e] - v0);
        if (dd < RANGE) {
            int p = atomicAdd(&cur[dd], 1);
            esrc[p] = src[e];
        }
    }
}

// ---------- prescale: xh = fp16(in_feat * ns) ----------
__global__ void prescale_kernel(const float* __restrict__ x, const float* __restrict__ ns,
                                _Float16* __restrict__ xh, int n) {
    int i = blockIdx.x * blockDim.x + threadIdx.x;   // one thread per 8 elements
    if (i >= n * (FEAT / 8)) return;
    int v = i >> 4;
    float w = ns[v];
    float4 t0 = ((const float4*)x)[i * 2];
    float4 t1 = ((const float4*)x)[i * 2 + 1];
    half8 h;
    h[0] = (_Float16)(t0.x * w); h[1] = (_Float16)(t0.y * w);
    h[2] = (_Float16)(t0.z * w); h[3] = (_Float16)(t0.w * w);
    h[4] = (_Float16)(t1.x * w); h[5] = (_Float16)(t1.y * w);
    h[6] = (_Float16)(t1.z * w); h[7] = (_Float16)(t1.w * w);
    ((float4*)xh)[i] = __builtin_bit_cast(float4, h);
}

// ---------- aggregation: fp16 gather (256 B/row), fp32 accumulate (round-3 proven) ----------
__global__ __launch_bounds__(256) void agg_kernel(const _Float16* __restrict__ x,
                                                  const int* __restrict__ offs,
                                                  const int* __restrict__ esrc,
                                                  const float* __restrict__ nd,
                                                  float* __restrict__ m, int n) {
    int gid = blockIdx.x * blockDim.x + threadIdx.x;
    int v = gid >> 6;
    if (v >= n) return;
    int lane = threadIdx.x & 63;
    int q = lane >> 4;       // quarter 0..3: independent edge stream, stride 4
    int c = lane & 15;       // 16 lanes x 16B cover a 128-half row
    int s0 = offs[v], s1 = offs[v + 1];
    float a0[8] = {0,0,0,0,0,0,0,0};
    float a1[8] = {0,0,0,0,0,0,0,0};
    float a2[8] = {0,0,0,0,0,0,0,0};
    float a3[8] = {0,0,0,0,0,0,0,0};
    int j = s0 + q;
    for (; j + 12 < s1; j += 16) {
        int e0 = esrc[j], e1 = esrc[j + 4], e2 = esrc[j + 8], e3 = esrc[j + 12];
        float4 r0 = ((const float4*)(x + (size_t)e0 * FEAT))[c];
        float4 r1 = ((const float4*)(x + (size_t)e1 * FEAT))[c];
        float4 r2 = ((const float4*)(x + (size_t)e2 * FEAT))[c];
        float4 r3 = ((const float4*)(x + (size_t)e3 * FEAT))[c];
        half8 h0 = __builtin_bit_cast(half8, r0);
        half8 h1 = __builtin_bit_cast(half8, r1);
        half8 h2 = __builtin_bit_cast(half8, r2);
        half8 h3 = __builtin_bit_cast(half8, r3);
        #pragma unroll
        for (int k = 0; k < 8; ++k) {
            a0[k] += (float)h0[k];
            a1[k] += (float)h1[k];
            a2[k] += (float)h2[k];
            a3[k] += (float)h3[k];
        }
    }
    for (; j < s1; j += 4) {
        int e0 = esrc[j];
        float4 r0 = ((const float4*)(x + (size_t)e0 * FEAT))[c];
        half8 h0 = __builtin_bit_cast(half8, r0);
        #pragma unroll
        for (int k = 0; k < 8; ++k) a0[k] += (float)h0[k];
    }
    float r[8];
    #pragma unroll
    for (int k = 0; k < 8; ++k) r[k] = (a0[k] + a1[k]) + (a2[k] + a3[k]);
    #pragma unroll
    for (int k = 0; k < 8; ++k) {
        r[k] += __shfl_xor(r[k], 16);
        r[k] += __shfl_xor(r[k], 32);
    }
    if (lane < 16) {
        float sc = nd[v];
        float4 o0, o1;
        o0.x = r[0] * sc; o0.y = r[1] * sc; o0.z = r[2] * sc; o0.w = r[3] * sc;
        o1.x = r[4] * sc; o1.y = r[5] * sc; o1.z = r[6] * sc; o1.w = r[7] * sc;
        ((float4*)(m + (size_t)v * FEAT))[c * 2] = o0;
        ((float4*)(m + (size_t)v * FEAT))[c * 2 + 1] = o1;
    }
}

// ---------- GEMM: MFMA f16 value+residual (r3-proven core) + coalesced LDS epilogue ----------
// 32x128 tile, 256 threads (4 waves: 2 row x 2 col), 80KB LDS -> 2 blocks/CU.
// acc = A16*W16 + A16*Wr + Ar*W16  (drops Ar*Wr ~ 2.4e-7 rel)
template<int MODE>   // 0: relu*ns -> fp16   1: last layer (fp32 h + threshold)
__global__ __launch_bounds__(256) void gemm_kernel(const float* __restrict__ M,
                                                   const _Float16* __restrict__ w16t,
                                                   const _Float16* __restrict__ wrt,
                                                   const float* __restrict__ bias,
                                                   const float* __restrict__ nsv,
                                                   _Float16* __restrict__ outh,
                                                   float* __restrict__ outf,
                                                   float* __restrict__ out2, int n) {
    __shared__ _Float16 sh[40960];     // 80KB: A16[4096] Ar[4096] W16[16384] Wr[16384]
    _Float16* A16s = sh;
    _Float16* Ars  = sh + 4096;
    _Float16* W16s = sh + 8192;
    _Float16* Wrs  = sh + 24576;
    int tid = threadIdx.x;
    int r0 = blockIdx.x * 32;

    // stage W (value+residual), XOR-swizzled 16B chunks: chunk ^= (col&7)
    #pragma unroll
    for (int j = 0; j < 8; ++j) {
        int i = tid + j * 256;             // 2048 float4 per array
        int col = i >> 4, ch = i & 15;
        int d = col * 16 + (ch ^ (col & 7));
        ((float4*)W16s)[d] = ((const float4*)w16t)[i];
        ((float4*)Wrs)[d]  = ((const float4*)wrt)[i];
    }
    // stage A rows r0..r0+31: fp32 -> fp16 value + residual, swizzled
    #pragma unroll
    for (int j = 0; j < 4; ++j) {
        int i = tid + j * 256;             // 1024 float4 of source fp32
        int row = i >> 5, c4 = i & 31;
        int gr = r0 + row;
        float4 v = make_float4(0.f, 0.f, 0.f, 0.f);
        if (gr < n) v = ((const float4*)(M + (size_t)gr * FEAT))[c4];
        half4v h, rr;
        h[0] = (_Float16)v.x; h[1] = (_Float16)v.y; h[2] = (_Float16)v.z; h[3] = (_Float16)v.w;
        rr[0] = (_Float16)(v.x - (float)h[0]); rr[1] = (_Float16)(v.y - (float)h[1]);
        rr[2] = (_Float16)(v.z - (float)h[2]); rr[3] = (_Float16)(v.w - (float)h[3]);
        int d = row * 128 + (((c4 >> 1) ^ (row & 7)) << 3) + ((c4 & 1) << 2);
        *(half4v*)(A16s + d) = h;
        *(half4v*)(Ars + d) = rr;
    }
    __syncthreads();

    int lane = tid & 63;
    int w = tid >> 6;
    int l15 = lane & 15;
    int q = lane >> 4;
    int rbase = (w & 1) * 16 + l15;        // A-frag row
    int cbase = (w >> 1) * 64;             // wave's 64-col strip

    f32x4 acc[4] = {{0.f,0.f,0.f,0.f},{0.f,0.f,0.f,0.f},{0.f,0.f,0.f,0.f},{0.f,0.f,0.f,0.f}};
    #pragma unroll
    for (int ks = 0; ks < 4; ++ks) {
        int chunk = ks * 4 + q;
        int aoff = rbase * 128 + ((chunk ^ (rbase & 7)) << 3);
        half8 a16 = *(const half8*)(A16s + aoff);
        half8 ar  = *(const half8*)(Ars + aoff);
        #pragma unroll
        for (int ct = 0; ct < 4; ++ct) {
            int col = cbase + ct * 16 + l15;
            int boff = col * 128 + ((chunk ^ (col & 7)) << 3);
            half8 b16 = *(const half8*)(W16s + boff);
            half8 br  = *(const half8*)(Wrs + boff);
            acc[ct] = __builtin_amdgcn_mfma_f32_16x16x32_f16(a16, b16, acc[ct], 0, 0, 0);
            acc[ct] = __builtin_amdgcn_mfma_f32_16x16x32_f16(a16, br,  acc[ct], 0, 0, 0);
            acc[ct] = __builtin_amdgcn_mfma_f32_16x16x32_f16(ar,  b16, acc[ct], 0, 0, 0);
        }
    }

    // epilogue via LDS restage -> coalesced float4 global stores.
    // C/D layout: col=lane&15, row=(lane>>4)*4+reg
    int rloc = (w & 1) * 16 + q * 4;
    __syncthreads();                       // all MFMA reads of sh done; safe to reuse
    if (MODE == 0) {
        _Float16* hstage = sh;             // 32x128 fp16 = 8KB
        float scv[4];
        #pragma unroll
        for (int reg = 0; reg < 4; ++reg) {
            int row = r0 + rloc + reg;
            scv[reg] = (row < n) ? nsv[row] : 1.0f;
        }
        #pragma unroll
        for (int ct = 0; ct < 4; ++ct) {
            int col = cbase + ct * 16 + l15;
            float b = bias[col];
            #pragma unroll
            for (int reg = 0; reg < 4; ++reg) {
                float h = acc[ct][reg] + b;
                h = h > 0.f ? h : 0.f;
                hstage[(rloc + reg) * 128 + col] = (_Float16)(h * scv[reg]);
            }
        }
        __syncthreads();
        #pragma unroll
        for (int j = 0; j < 2; ++j) {
            int i = tid + j * 256;         // 512 float4 (8 halfs each)
            int row = i >> 4, c16 = i & 15;
            if (r0 + row < n)
                ((float4*)(outh + (size_t)(r0 + row) * FEAT))[c16] =
                    ((const float4*)hstage)[i];
        }
    } else {
        float* fstage = (float*)sh;        // 32x128 fp32 = 16KB
        #pragma unroll
        for (int ct = 0; ct < 4; ++ct) {
            int col = cbase + ct * 16 + l15;
            float b = bias[col];
            #pragma unroll
            for (int reg = 0; reg < 4; ++reg) {
                float h = acc[ct][reg] + b;
                h = h > 0.f ? h : 0.f;
                fstage[(rloc + reg) * 128 + col] = h;
            }
        }
        __syncthreads();
        #pragma unroll
        for (int j = 0; j < 4; ++j) {
            int i = tid + j * 256;         // 1024 float4
            int row = i >> 5, c8 = i & 31;
            if (r0 + row < n) {
                float4 hv = ((const float4*)fstage)[i];
                ((float4*)(outf + (size_t)(r0 + row) * FEAT))[c8] = hv;
                float4 cv;
                cv.x = hv.x >= 0.5f ? 1.f : 0.f; cv.y = hv.y >= 0.5f ? 1.f : 0.f;
                cv.z = hv.z >= 0.5f ? 1.f : 0.f; cv.w = hv.w >= 0.5f ? 1.f : 0.f;
                ((float4*)(out2 + (size_t)(r0 + row) * FEAT))[c8] = cv;
            }
        }
    }
}

extern "C" void kernel_launch(void* const* d_in, const int* in_sizes, int n_in,
                              void* d_out, int out_size, void* d_ws, size_t ws_size,
                              hipStream_t stream) {
    const float* in_feat = (const float*)d_in[0];
    const int*   src     = (const int*)d_in[1];
    const int*   dst     = (const int*)d_in[2];
    const float* W[5] = {(const float*)d_in[3], (const float*)d_in[5], (const float*)d_in[7],
                         (const float*)d_in[9], (const float*)d_in[11]};
    const float* B[5] = {(const float*)d_in[4], (const float*)d_in[6], (const float*)d_in[8],
                         (const float*)d_in[10], (const float*)d_in[12]};
    const int E = in_sizes[1];
    const int N = in_sizes[0] / FEAT;
    const int NRANGE = (N + RANGE - 1) / RANGE;       // 4
    const int NP = NRANGE * RANGE;                    // 51200
    const size_t MTOT = (size_t)NP * NSLICE;          // 3,276,800

    char* ws = (char*)d_ws;
    size_t off = 0;
    auto alloc = [&](size_t bytes) { size_t o = off; off += (bytes + 255) & ~size_t(255); return o; };
    unsigned* partialD = (unsigned*)(ws + alloc(MTOT * 2));
    size_t    pS_off   = alloc(MTOT * 2);
    unsigned* partialS = (unsigned*)(ws + pS_off);
    int*      esrc     = (int*)(ws + pS_off);          // aliases partialS (dead after prep1)
    size_t    cV_off   = alloc(MTOT * 4);
    int*      cursorV  = (int*)(ws + cV_off);
    _Float16* xh       = (_Float16*)(ws + cV_off);     // aliases cursorV (dead after fill)
    float*    ns       = (float*)(ws + alloc((size_t)N * 4));
    float*    nd       = (float*)(ws + alloc((size_t)N * 4));
    int*      offsc    = (int*)(ws + alloc((size_t)(N + 1) * 4));
    int*      blockSums = (int*)(ws + alloc(1024));
    _Float16* w16t     = (_Float16*)(ws + alloc(5 * 16384 * 2));
    _Float16* wrt      = (_Float16*)(ws + alloc(5 * 16384 * 2));

    float* out_h = (float*)d_out;                     // m scratch; final h
    float* out_c = out_h + (size_t)N * FEAT;          // threshold output

    const int histBlocks = 2 * NRANGE * NSLICE;       // 512
    const int scanBlocks = NP / 256;                  // 200

    hist_kernel<<<histBlocks, 1024, 0, stream>>>(src, dst, partialD, partialS, E, NP);
    prep1_kernel<<<scanBlocks + 320, 256, 0, stream>>>((const unsigned short*)partialD,
                                                       (const unsigned short*)partialS,
                                                       blockSums, ns, nd,
                                                       W[0], W[1], W[2], W[3], W[4],
                                                       w16t, wrt, NP, N, scanBlocks);
    prep2_kernel<<<scanBlocks, 256, 0, stream>>>((const unsigned short*)partialD, blockSums,
                                                 cursorV, offsc, NP, N, scanBlocks);
    fill_kernel<<<NRANGE * NSLICE, 1024, 0, stream>>>(src, dst, cursorV, esrc, E, NP);
    // prescale AFTER fill: xh aliases cursorV
    prescale_kernel<<<(N * (FEAT / 8) + 255) / 256, 256, 0, stream>>>(in_feat, ns, xh, N);

    const int agg_blocks = (int)(((size_t)N * 64 + 255) / 256);   // 12500
    const int gemm_blocks = (N + 31) / 32;                        // 1563

    for (int l = 0; l < 5; ++l) {
        agg_kernel<<<agg_blocks, 256, 0, stream>>>(xh, offsc, esrc, nd, out_h, N);
        if (l < 4)
            gemm_kernel<0><<<gemm_blocks, 256, 0, stream>>>(out_h, w16t + (size_t)l * 16384,
                                                            wrt + (size_t)l * 16384, B[l], ns,
                                                            xh, nullptr, nullptr, N);
        else
            gemm_kernel<1><<<gemm_blocks, 256, 0, stream>>>(out_h, w16t + (size_t)l * 16384,
                                                            wrt + (size_t)l * 16384, B[l], nullptr,
                                                            nullptr, out_h, out_c, N);
    }
}

// Round 9
// 416.770 us; speedup vs baseline: 3.4002x; 1.0409x over previous
//
#include <hip/hip_runtime.h>

#define FEAT 128
#define NSLICE 64
#define NPC 51200          // padded node count (problem-fixed N=50000)
#define RANGE_F 25600      // fill cursor tile (2 range passes)

typedef _Float16 half8 __attribute__((ext_vector_type(8)));
typedef _Float16 half4v __attribute__((ext_vector_type(4)));
typedef float f32x4 __attribute__((ext_vector_type(4)));

// ---------- hist: one pass, full-node packed histogram in 102.4KB dynamic LDS ----------
// 128 blocks: b>>6 = 0 (dst -> partialD) / 1 (src -> partialS); s = b&63 edge slice.
__global__ __launch_bounds__(1024) void hist_kernel(const int* __restrict__ src,
                                                    const int* __restrict__ dst,
                                                    unsigned* __restrict__ partialD,
                                                    unsigned* __restrict__ partialS,
                                                    int E) {
    extern __shared__ unsigned hpk[];                // NPC/2 = 25600 words
    int b = blockIdx.x;
    int halfsel = b >> 6;
    int s = b & 63;
    const int* arr = halfsel ? src : dst;
    unsigned* out = halfsel ? partialS : partialD;
    int tid = threadIdx.x;
    for (int i = tid; i < NPC / 2; i += 1024) hpk[i] = 0;
    __syncthreads();
    int e0 = (int)((long long)E * s / NSLICE);
    int e1 = (int)((long long)E * (s + 1) / NSLICE);
    for (int e = e0 + tid; e < e1; e += 1024) {
        unsigned d = (unsigned)arr[e];               // < 50000 < NPC always
        atomicAdd(&hpk[d >> 1], (d & 1) ? 65536u : 1u);
    }
    __syncthreads();
    size_t wbase = ((size_t)s * NPC) >> 1;
    for (int i = tid; i < NPC / 2; i += 1024) out[wbase + i] = hpk[i];
}

// ---------- prep1: blocks [0,sb): slice sums + norms + blockSums
//                   blocks [sb, sb+320): W fp16 value+residual transpose ----------
__global__ __launch_bounds__(256) void prep1_kernel(const unsigned short* __restrict__ pD,
                                                    const unsigned short* __restrict__ pS,
                                                    int* __restrict__ blockSums,
                                                    float* __restrict__ ns,
                                                    float* __restrict__ nd,
                                                    const float* __restrict__ Wa,
                                                    const float* __restrict__ Wb,
                                                    const float* __restrict__ Wc,
                                                    const float* __restrict__ Wd,
                                                    const float* __restrict__ We,
                                                    _Float16* __restrict__ w16t,
                                                    _Float16* __restrict__ wrt,
                                                    int n, int sb) {
    int tid = threadIdx.x;
    int b = blockIdx.x;
    if (b < sb) {
        __shared__ int buf[256];
        int v = b * 256 + tid;
        int ssum = 0, osum = 0;
        #pragma unroll
        for (int s = 0; s < NSLICE; ++s) {
            ssum += pD[(size_t)s * NPC + v];
            osum += pS[(size_t)s * NPC + v];
        }
        if (v < n) {
            ns[v] = 1.0f / sqrtf((float)(osum < 1 ? 1 : osum));
            nd[v] = 1.0f / sqrtf((float)(ssum < 1 ? 1 : ssum));
        }
        buf[tid] = ssum;
        __syncthreads();
        #pragma unroll
        for (int off = 1; off < 256; off <<= 1) {
            int t = (tid >= off) ? buf[tid - off] : 0;
            __syncthreads();
            buf[tid] += t;
            __syncthreads();
        }
        if (tid == 255) blockSums[b] = buf[255];
    } else {
        int gid = (b - sb) * 256 + tid;              // 0 .. 81919
        int l = gid >> 14;
        int idx = gid & 16383;
        int col = idx >> 7;
        int k = idx & 127;
        const float* Wp = (l == 0) ? Wa : (l == 1) ? Wb : (l == 2) ? Wc : (l == 3) ? Wd : We;
        float w = Wp[k * FEAT + col];
        _Float16 h = (_Float16)w;
        _Float16 r = (_Float16)(w - (float)h);
        w16t[gid] = h;
        wrt[gid] = r;
    }
}

// ---------- prep2: blocks [0,nb): merged scan2+scan3, cursorVT [slice][node] layout
//                   blocks [nb, ...): prescale xh = fp16(in_feat * ns) ----------
__global__ __launch_bounds__(256) void prep2_kernel(const unsigned short* __restrict__ pD,
                                                    const int* __restrict__ blockSums,
                                                    int* __restrict__ cursorVT,
                                                    int* __restrict__ offsc,
                                                    const float* __restrict__ xf,
                                                    const float* __restrict__ ns,
                                                    _Float16* __restrict__ xh,
                                                    int n, int nb) {
    int tid = threadIdx.x;
    int b = blockIdx.x;
    if (b < nb) {
        __shared__ int buf[256];
        int bsv = (tid < nb) ? blockSums[tid] : 0;
        buf[tid] = bsv;
        __syncthreads();
        #pragma unroll
        for (int off = 1; off < 256; off <<= 1) {
            int t = (tid >= off) ? buf[tid - off] : 0;
            __syncthreads();
            buf[tid] += t;
            __syncthreads();
        }
        int myoff = (b > 0) ? buf[b - 1] : 0;
        __syncthreads();
        int v = b * 256 + tid;
        int ssum = 0;
        #pragma unroll
        for (int s = 0; s < NSLICE; ++s) ssum += pD[(size_t)s * NPC + v];
        buf[tid] = ssum;
        __syncthreads();
        #pragma unroll
        for (int off = 1; off < 256; off <<= 1) {
            int t = (tid >= off) ? buf[tid - off] : 0;
            __syncthreads();
            buf[tid] += t;
            __syncthreads();
        }
        int o = myoff + buf[tid] - ssum;
        if (v <= n) offsc[v] = o;      // pad nodes have zero edges -> v==n gets total
        #pragma unroll
        for (int s = 0; s < NSLICE; ++s) {
            int val = pD[(size_t)s * NPC + v];
            cursorVT[(size_t)s * NPC + v] = o;       // coalesced per-s
            o += val;
        }
    } else {
        int i = (b - nb) * 256 + tid;                // one thread per 8 elements
        if (i < n * (FEAT / 8)) {
            int v = i >> 4;
            float w = ns[v];
            float4 t0 = ((const float4*)xf)[i * 2];
            float4 t1 = ((const float4*)xf)[i * 2 + 1];
            half8 h;
            h[0] = (_Float16)(t0.x * w); h[1] = (_Float16)(t0.y * w);
            h[2] = (_Float16)(t0.z * w); h[3] = (_Float16)(t0.w * w);
            h[4] = (_Float16)(t1.x * w); h[5] = (_Float16)(t1.y * w);
            h[6] = (_Float16)(t1.z * w); h[7] = (_Float16)(t1.w * w);
            ((float4*)xh)[i] = __builtin_bit_cast(float4, h);
        }
    }
}

// ---------- fill: 2 range passes, contiguous cursor tile load, XCD-swizzled slices ----------
__global__ __launch_bounds__(1024) void fill_kernel(const int* __restrict__ src,
                                                    const int* __restrict__ dst,
                                                    const int* __restrict__ cursorVT,
                                                    int* __restrict__ esrc, int E) {
    extern __shared__ int cur[];                     // RANGE_F ints = 102.4KB
    int b = blockIdx.x;
    int r = b / NSLICE;
    int inner = b % NSLICE;
    int s = ((inner & 7) << 3) | (inner >> 3);
    int v0 = r * RANGE_F;
    int tid = threadIdx.x;
    const int4* csrc = (const int4*)(cursorVT + (size_t)s * NPC + v0);
    for (int i = tid; i < RANGE_F / 4; i += 1024)
        ((int4*)cur)[i] = csrc[i];
    __syncthreads();
    int e0 = (int)((long long)E * s / NSLICE);
    int e1 = (int)((long long)E * (s + 1) / NSLICE);
    for (int e = e0 + tid; e < e1; e += 1024) {
        unsigned dd = (unsigned)(dst[e] - v0);
        if (dd < RANGE_F) {
            int p = atomicAdd(&cur[dd], 1);
            esrc[p] = src[e];
        }
    }
}

// ---------- aggregation: fp16 gather (256 B/row), fp32 accumulate (r8-proven, unchanged) ----
__global__ __launch_bounds__(256) void agg_kernel(const _Float16* __restrict__ x,
                                                  const int* __restrict__ offs,
                                                  const int* __restrict__ esrc,
                                                  const float* __restrict__ nd,
                                                  float* __restrict__ m, int n) {
    int gid = blockIdx.x * blockDim.x + threadIdx.x;
    int v = gid >> 6;
    if (v >= n) return;
    int lane = threadIdx.x & 63;
    int q = lane >> 4;       // quarter 0..3: independent edge stream, stride 4
    int c = lane & 15;       // 16 lanes x 16B cover a 128-half row
    int s0 = offs[v], s1 = offs[v + 1];
    float a0[8] = {0,0,0,0,0,0,0,0};
    float a1[8] = {0,0,0,0,0,0,0,0};
    float a2[8] = {0,0,0,0,0,0,0,0};
    float a3[8] = {0,0,0,0,0,0,0,0};
    int j = s0 + q;
    for (; j + 12 < s1; j += 16) {
        int e0 = esrc[j], e1 = esrc[j + 4], e2 = esrc[j + 8], e3 = esrc[j + 12];
        float4 r0 = ((const float4*)(x + (size_t)e0 * FEAT))[c];
        float4 r1 = ((const float4*)(x + (size_t)e1 * FEAT))[c];
        float4 r2 = ((const float4*)(x + (size_t)e2 * FEAT))[c];
        float4 r3 = ((const float4*)(x + (size_t)e3 * FEAT))[c];
        half8 h0 = __builtin_bit_cast(half8, r0);
        half8 h1 = __builtin_bit_cast(half8, r1);
        half8 h2 = __builtin_bit_cast(half8, r2);
        half8 h3 = __builtin_bit_cast(half8, r3);
        #pragma unroll
        for (int k = 0; k < 8; ++k) {
            a0[k] += (float)h0[k];
            a1[k] += (float)h1[k];
            a2[k] += (float)h2[k];
            a3[k] += (float)h3[k];
        }
    }
    for (; j < s1; j += 4) {
        int e0 = esrc[j];
        float4 r0 = ((const float4*)(x + (size_t)e0 * FEAT))[c];
        half8 h0 = __builtin_bit_cast(half8, r0);
        #pragma unroll
        for (int k = 0; k < 8; ++k) a0[k] += (float)h0[k];
    }
    float r[8];
    #pragma unroll
    for (int k = 0; k < 8; ++k) r[k] = (a0[k] + a1[k]) + (a2[k] + a3[k]);
    #pragma unroll
    for (int k = 0; k < 8; ++k) {
        r[k] += __shfl_xor(r[k], 16);
        r[k] += __shfl_xor(r[k], 32);
    }
    if (lane < 16) {
        float sc = nd[v];
        float4 o0, o1;
        o0.x = r[0] * sc; o0.y = r[1] * sc; o0.z = r[2] * sc; o0.w = r[3] * sc;
        o1.x = r[4] * sc; o1.y = r[5] * sc; o1.z = r[6] * sc; o1.w = r[7] * sc;
        ((float4*)(m + (size_t)v * FEAT))[c * 2] = o0;
        ((float4*)(m + (size_t)v * FEAT))[c * 2 + 1] = o1;
    }
}

// ---------- GEMM: MFMA f16 value+residual + coalesced LDS epilogue (r8-proven, unchanged) ----
template<int MODE>   // 0: relu*ns -> fp16   1: last layer (fp32 h + threshold)
__global__ __launch_bounds__(256) void gemm_kernel(const float* __restrict__ M,
                                                   const _Float16* __restrict__ w16t,
                                                   const _Float16* __restrict__ wrt,
                                                   const float* __restrict__ bias,
                                                   const float* __restrict__ nsv,
                                                   _Float16* __restrict__ outh,
                                                   float* __restrict__ outf,
                                                   float* __restrict__ out2, int n) {
    __shared__ _Float16 sh[40960];     // 80KB: A16[4096] Ar[4096] W16[16384] Wr[16384]
    _Float16* A16s = sh;
    _Float16* Ars  = sh + 4096;
    _Float16* W16s = sh + 8192;
    _Float16* Wrs  = sh + 24576;
    int tid = threadIdx.x;
    int r0 = blockIdx.x * 32;

    #pragma unroll
    for (int j = 0; j < 8; ++j) {
        int i = tid + j * 256;             // 2048 float4 per array
        int col = i >> 4, ch = i & 15;
        int d = col * 16 + (ch ^ (col & 7));
        ((float4*)W16s)[d] = ((const float4*)w16t)[i];
        ((float4*)Wrs)[d]  = ((const float4*)wrt)[i];
    }
    #pragma unroll
    for (int j = 0; j < 4; ++j) {
        int i = tid + j * 256;             // 1024 float4 of source fp32
        int row = i >> 5, c4 = i & 31;
        int gr = r0 + row;
        float4 v = make_float4(0.f, 0.f, 0.f, 0.f);
        if (gr < n) v = ((const float4*)(M + (size_t)gr * FEAT))[c4];
        half4v h, rr;
        h[0] = (_Float16)v.x; h[1] = (_Float16)v.y; h[2] = (_Float16)v.z; h[3] = (_Float16)v.w;
        rr[0] = (_Float16)(v.x - (float)h[0]); rr[1] = (_Float16)(v.y - (float)h[1]);
        rr[2] = (_Float16)(v.z - (float)h[2]); rr[3] = (_Float16)(v.w - (float)h[3]);
        int d = row * 128 + (((c4 >> 1) ^ (row & 7)) << 3) + ((c4 & 1) << 2);
        *(half4v*)(A16s + d) = h;
        *(half4v*)(Ars + d) = rr;
    }
    __syncthreads();

    int lane = tid & 63;
    int w = tid >> 6;
    int l15 = lane & 15;
    int q = lane >> 4;
    int rbase = (w & 1) * 16 + l15;        // A-frag row
    int cbase = (w >> 1) * 64;             // wave's 64-col strip

    f32x4 acc[4] = {{0.f,0.f,0.f,0.f},{0.f,0.f,0.f,0.f},{0.f,0.f,0.f,0.f},{0.f,0.f,0.f,0.f}};
    #pragma unroll
    for (int ks = 0; ks < 4; ++ks) {
        int chunk = ks * 4 + q;
        int aoff = rbase * 128 + ((chunk ^ (rbase & 7)) << 3);
        half8 a16 = *(const half8*)(A16s + aoff);
        half8 ar  = *(const half8*)(Ars + aoff);
        #pragma unroll
        for (int ct = 0; ct < 4; ++ct) {
            int col = cbase + ct * 16 + l15;
            int boff = col * 128 + ((chunk ^ (col & 7)) << 3);
            half8 b16 = *(const half8*)(W16s + boff);
            half8 br  = *(const half8*)(Wrs + boff);
            acc[ct] = __builtin_amdgcn_mfma_f32_16x16x32_f16(a16, b16, acc[ct], 0, 0, 0);
            acc[ct] = __builtin_amdgcn_mfma_f32_16x16x32_f16(a16, br,  acc[ct], 0, 0, 0);
            acc[ct] = __builtin_amdgcn_mfma_f32_16x16x32_f16(ar,  b16, acc[ct], 0, 0, 0);
        }
    }

    int rloc = (w & 1) * 16 + q * 4;
    __syncthreads();                       // all MFMA reads of sh done; safe to reuse
    if (MODE == 0) {
        _Float16* hstage = sh;             // 32x128 fp16 = 8KB
        float scv[4];
        #pragma unroll
        for (int reg = 0; reg < 4; ++reg) {
            int row = r0 + rloc + reg;
            scv[reg] = (row < n) ? nsv[row] : 1.0f;
        }
        #pragma unroll
        for (int ct = 0; ct < 4; ++ct) {
            int col = cbase + ct * 16 + l15;
            float b = bias[col];
            #pragma unroll
            for (int reg = 0; reg < 4; ++reg) {
                float h = acc[ct][reg] + b;
                h = h > 0.f ? h : 0.f;
                hstage[(rloc + reg) * 128 + col] = (_Float16)(h * scv[reg]);
            }
        }
        __syncthreads();
        #pragma unroll
        for (int j = 0; j < 2; ++j) {
            int i = tid + j * 256;         // 512 float4 (8 halfs each)
            int row = i >> 4, c16 = i & 15;
            if (r0 + row < n)
                ((float4*)(outh + (size_t)(r0 + row) * FEAT))[c16] =
                    ((const float4*)hstage)[i];
        }
    } else {
        float* fstage = (float*)sh;        // 32x128 fp32 = 16KB
        #pragma unroll
        for (int ct = 0; ct < 4; ++ct) {
            int col = cbase + ct * 16 + l15;
            float b = bias[col];
            #pragma unroll
            for (int reg = 0; reg < 4; ++reg) {
                float h = acc[ct][reg] + b;
                h = h > 0.f ? h : 0.f;
                fstage[(rloc + reg) * 128 + col] = h;
            }
        }
        __syncthreads();
        #pragma unroll
        for (int j = 0; j < 4; ++j) {
            int i = tid + j * 256;         // 1024 float4
            int row = i >> 5, c8 = i & 31;
            if (r0 + row < n) {
                float4 hv = ((const float4*)fstage)[i];
                ((float4*)(outf + (size_t)(r0 + row) * FEAT))[c8] = hv;
                float4 cv;
                cv.x = hv.x >= 0.5f ? 1.f : 0.f; cv.y = hv.y >= 0.5f ? 1.f : 0.f;
                cv.z = hv.z >= 0.5f ? 1.f : 0.f; cv.w = hv.w >= 0.5f ? 1.f : 0.f;
                ((float4*)(out2 + (size_t)(r0 + row) * FEAT))[c8] = cv;
            }
        }
    }
}

extern "C" void kernel_launch(void* const* d_in, const int* in_sizes, int n_in,
                              void* d_out, int out_size, void* d_ws, size_t ws_size,
                              hipStream_t stream) {
    const float* in_feat = (const float*)d_in[0];
    const int*   src     = (const int*)d_in[1];
    const int*   dst     = (const int*)d_in[2];
    const float* W[5] = {(const float*)d_in[3], (const float*)d_in[5], (const float*)d_in[7],
                         (const float*)d_in[9], (const float*)d_in[11]};
    const float* B[5] = {(const float*)d_in[4], (const float*)d_in[6], (const float*)d_in[8],
                         (const float*)d_in[10], (const float*)d_in[12]};
    const int E = in_sizes[1];
    const int N = in_sizes[0] / FEAT;
    const size_t MTOT = (size_t)NPC * NSLICE;         // 3,276,800

    char* ws = (char*)d_ws;
    size_t off = 0;
    auto alloc = [&](size_t bytes) { size_t o = off; off += (bytes + 255) & ~size_t(255); return o; };
    unsigned* partialD = (unsigned*)(ws + alloc(MTOT * 2));
    size_t    pS_off   = alloc(MTOT * 2);
    unsigned* partialS = (unsigned*)(ws + pS_off);
    int*      esrc     = (int*)(ws + pS_off);          // aliases partialS (dead after prep1)
    int*      cursorVT = (int*)(ws + alloc(MTOT * 4));
    _Float16* xh       = (_Float16*)(ws + alloc((size_t)N * FEAT * 2));
    float*    ns       = (float*)(ws + alloc((size_t)N * 4));
    float*    nd       = (float*)(ws + alloc((size_t)N * 4));
    int*      offsc    = (int*)(ws + alloc((size_t)(N + 1) * 4));
    int*      blockSums = (int*)(ws + alloc(1024));
    _Float16* w16t     = (_Float16*)(ws + alloc(5 * 16384 * 2));
    _Float16* wrt      = (_Float16*)(ws + alloc(5 * 16384 * 2));

    float* out_h = (float*)d_out;                     // m scratch; final h
    float* out_c = out_h + (size_t)N * FEAT;          // threshold output

    const int scanBlocks = NPC / 256;                 // 200
    const int psBlocks = (N * (FEAT / 8) + 255) / 256; // 3125

    hist_kernel<<<2 * NSLICE, 1024, (NPC / 2) * 4, stream>>>(src, dst, partialD, partialS, E);
    prep1_kernel<<<scanBlocks + 320, 256, 0, stream>>>((const unsigned short*)partialD,
                                                       (const unsigned short*)partialS,
                                                       blockSums, ns, nd,
                                                       W[0], W[1], W[2], W[3], W[4],
                                                       w16t, wrt, N, scanBlocks);
    prep2_kernel<<<scanBlocks + psBlocks, 256, 0, stream>>>((const unsigned short*)partialD,
                                                            blockSums, cursorVT, offsc,
                                                            in_feat, ns, xh, N, scanBlocks);
    fill_kernel<<<(NPC / RANGE_F) * NSLICE, 1024, RANGE_F * 4, stream>>>(src, dst, cursorVT,
                                                                         esrc, E);

    const int agg_blocks = (int)(((size_t)N * 64 + 255) / 256);   // 12500
    const int gemm_blocks = (N + 31) / 32;                        // 1563

    for (int l = 0; l < 5; ++l) {
        agg_kernel<<<agg_blocks, 256, 0, stream>>>(xh, offsc, esrc, nd, out_h, N);
        if (l < 4)
            gemm_kernel<0><<<gemm_blocks, 256, 0, stream>>>(out_h, w16t + (size_t)l * 16384,
                                                            wrt + (size_t)l * 16384, B[l], ns,
                                                            xh, nullptr, nullptr, N);
        else
            gemm_kernel<1><<<gemm_blocks, 256, 0, stream>>>(out_h, w16t + (size_t)l * 16384,
                                                            wrt + (size_t)l * 16384, B[l], nullptr,
                                                            nullptr, out_h, out_c, N);
    }
}

// Round 10
// 406.611 us; speedup vs baseline: 3.4852x; 1.0250x over previous
//
#include <hip/hip_runtime.h>

#define FEAT 128
#define NSLICE 64
#define NPC 51200          // padded node count (problem-fixed N=50000)
#define RANGE_F 25600      // fill cursor tile (2 range passes)

typedef _Float16 half8 __attribute__((ext_vector_type(8)));
typedef float f32x4 __attribute__((ext_vector_type(4)));

// ---------- hist: one pass, full-node packed histogram in 102.4KB dynamic LDS ----------
__global__ __launch_bounds__(1024) void hist_kernel(const int* __restrict__ src,
                                                    const int* __restrict__ dst,
                                                    unsigned* __restrict__ partialD,
                                                    unsigned* __restrict__ partialS,
                                                    int E) {
    extern __shared__ unsigned hpk[];                // NPC/2 = 25600 words
    int b = blockIdx.x;
    int halfsel = b >> 6;
    int s = b & 63;
    const int* arr = halfsel ? src : dst;
    unsigned* out = halfsel ? partialS : partialD;
    int tid = threadIdx.x;
    for (int i = tid; i < NPC / 2; i += 1024) hpk[i] = 0;
    __syncthreads();
    int e0 = (int)((long long)E * s / NSLICE);
    int e1 = (int)((long long)E * (s + 1) / NSLICE);
    for (int e = e0 + tid; e < e1; e += 1024) {
        unsigned d = (unsigned)arr[e];
        atomicAdd(&hpk[d >> 1], (d & 1) ? 65536u : 1u);
    }
    __syncthreads();
    size_t wbase = ((size_t)s * NPC) >> 1;
    for (int i = tid; i < NPC / 2; i += 1024) out[wbase + i] = hpk[i];
}

// ---------- prep1: blocks [0,sb): slice sums + norms + blockSums
//                   blocks [sb, sb+320): W fp16 value+residual transpose ----------
__global__ __launch_bounds__(256) void prep1_kernel(const unsigned short* __restrict__ pD,
                                                    const unsigned short* __restrict__ pS,
                                                    int* __restrict__ blockSums,
                                                    float* __restrict__ ns,
                                                    float* __restrict__ nd,
                                                    const float* __restrict__ Wa,
                                                    const float* __restrict__ Wb,
                                                    const float* __restrict__ Wc,
                                                    const float* __restrict__ Wd,
                                                    const float* __restrict__ We,
                                                    _Float16* __restrict__ w16t,
                                                    _Float16* __restrict__ wrt,
                                                    int n, int sb) {
    int tid = threadIdx.x;
    int b = blockIdx.x;
    if (b < sb) {
        __shared__ int buf[256];
        int v = b * 256 + tid;
        int ssum = 0, osum = 0;
        #pragma unroll
        for (int s = 0; s < NSLICE; ++s) {
            ssum += pD[(size_t)s * NPC + v];
            osum += pS[(size_t)s * NPC + v];
        }
        if (v < n) {
            ns[v] = 1.0f / sqrtf((float)(osum < 1 ? 1 : osum));
            nd[v] = 1.0f / sqrtf((float)(ssum < 1 ? 1 : ssum));
        }
        buf[tid] = ssum;
        __syncthreads();
        #pragma unroll
        for (int off = 1; off < 256; off <<= 1) {
            int t = (tid >= off) ? buf[tid - off] : 0;
            __syncthreads();
            buf[tid] += t;
            __syncthreads();
        }
        if (tid == 255) blockSums[b] = buf[255];
    } else {
        int gid = (b - sb) * 256 + tid;              // 0 .. 81919
        int l = gid >> 14;
        int idx = gid & 16383;
        int col = idx >> 7;
        int k = idx & 127;
        const float* Wp = (l == 0) ? Wa : (l == 1) ? Wb : (l == 2) ? Wc : (l == 3) ? Wd : We;
        float w = Wp[k * FEAT + col];
        _Float16 h = (_Float16)w;
        _Float16 r = (_Float16)(w - (float)h);
        w16t[gid] = h;
        wrt[gid] = r;
    }
}

// ---------- prep2: blocks [0,nb): merged scan2+scan3, cursorVT [slice][node] layout
//                   blocks [nb, ...): prescale xh = fp16(in_feat * ns) ----------
__global__ __launch_bounds__(256) void prep2_kernel(const unsigned short* __restrict__ pD,
                                                    const int* __restrict__ blockSums,
                                                    int* __restrict__ cursorVT,
                                                    int* __restrict__ offsc,
                                                    const float* __restrict__ xf,
                                                    const float* __restrict__ ns,
                                                    _Float16* __restrict__ xh,
                                                    int n, int nb) {
    int tid = threadIdx.x;
    int b = blockIdx.x;
    if (b < nb) {
        __shared__ int buf[256];
        int bsv = (tid < nb) ? blockSums[tid] : 0;
        buf[tid] = bsv;
        __syncthreads();
        #pragma unroll
        for (int off = 1; off < 256; off <<= 1) {
            int t = (tid >= off) ? buf[tid - off] : 0;
            __syncthreads();
            buf[tid] += t;
            __syncthreads();
        }
        int myoff = (b > 0) ? buf[b - 1] : 0;
        __syncthreads();
        int v = b * 256 + tid;
        int ssum = 0;
        #pragma unroll
        for (int s = 0; s < NSLICE; ++s) ssum += pD[(size_t)s * NPC + v];
        buf[tid] = ssum;
        __syncthreads();
        #pragma unroll
        for (int off = 1; off < 256; off <<= 1) {
            int t = (tid >= off) ? buf[tid - off] : 0;
            __syncthreads();
            buf[tid] += t;
            __syncthreads();
        }
        int o = myoff + buf[tid] - ssum;
        if (v <= n) offsc[v] = o;      // pad nodes have zero edges -> v==n gets total
        #pragma unroll
        for (int s = 0; s < NSLICE; ++s) {
            int val = pD[(size_t)s * NPC + v];
            cursorVT[(size_t)s * NPC + v] = o;       // coalesced per-s
            o += val;
        }
    } else {
        int i = (b - nb) * 256 + tid;                // one thread per 8 elements
        if (i < n * (FEAT / 8)) {
            int v = i >> 4;
            float w = ns[v];
            float4 t0 = ((const float4*)xf)[i * 2];
            float4 t1 = ((const float4*)xf)[i * 2 + 1];
            half8 h;
            h[0] = (_Float16)(t0.x * w); h[1] = (_Float16)(t0.y * w);
            h[2] = (_Float16)(t0.z * w); h[3] = (_Float16)(t0.w * w);
            h[4] = (_Float16)(t1.x * w); h[5] = (_Float16)(t1.y * w);
            h[6] = (_Float16)(t1.z * w); h[7] = (_Float16)(t1.w * w);
            ((float4*)xh)[i] = __builtin_bit_cast(float4, h);
        }
    }
}

// ---------- fill: 2 range passes, contiguous cursor tile load, XCD-swizzled slices ----------
__global__ __launch_bounds__(1024) void fill_kernel(const int* __restrict__ src,
                                                    const int* __restrict__ dst,
                                                    const int* __restrict__ cursorVT,
                                                    int* __restrict__ esrc, int E) {
    extern __shared__ int cur[];                     // RANGE_F ints = 102.4KB
    int b = blockIdx.x;
    int r = b / NSLICE;
    int inner = b % NSLICE;
    int s = ((inner & 7) << 3) | (inner >> 3);
    int v0 = r * RANGE_F;
    int tid = threadIdx.x;
    const int4* csrc = (const int4*)(cursorVT + (size_t)s * NPC + v0);
    for (int i = tid; i < RANGE_F / 4; i += 1024)
        ((int4*)cur)[i] = csrc[i];
    __syncthreads();
    int e0 = (int)((long long)E * s / NSLICE);
    int e1 = (int)((long long)E * (s + 1) / NSLICE);
    for (int e = e0 + tid; e < e1; e += 1024) {
        unsigned dd = (unsigned)(dst[e] - v0);
        if (dd < RANGE_F) {
            int p = atomicAdd(&cur[dd], 1);
            esrc[p] = src[e];
        }
    }
}

// ---------- aggregation: fp16 gather, fp32 accumulate, fp16 m output ----------
__global__ __launch_bounds__(256) void agg_kernel(const _Float16* __restrict__ x,
                                                  const int* __restrict__ offs,
                                                  const int* __restrict__ esrc,
                                                  const float* __restrict__ nd,
                                                  _Float16* __restrict__ m, int n) {
    int gid = blockIdx.x * blockDim.x + threadIdx.x;
    int v = gid >> 6;
    if (v >= n) return;
    int lane = threadIdx.x & 63;
    int q = lane >> 4;       // quarter 0..3: independent edge stream, stride 4
    int c = lane & 15;       // 16 lanes x 16B cover a 128-half row
    int s0 = offs[v], s1 = offs[v + 1];
    float a0[8] = {0,0,0,0,0,0,0,0};
    float a1[8] = {0,0,0,0,0,0,0,0};
    float a2[8] = {0,0,0,0,0,0,0,0};
    float a3[8] = {0,0,0,0,0,0,0,0};
    int j = s0 + q;
    for (; j + 12 < s1; j += 16) {
        int e0 = esrc[j], e1 = esrc[j + 4], e2 = esrc[j + 8], e3 = esrc[j + 12];
        float4 r0 = ((const float4*)(x + (size_t)e0 * FEAT))[c];
        float4 r1 = ((const float4*)(x + (size_t)e1 * FEAT))[c];
        float4 r2 = ((const float4*)(x + (size_t)e2 * FEAT))[c];
        float4 r3 = ((const float4*)(x + (size_t)e3 * FEAT))[c];
        half8 h0 = __builtin_bit_cast(half8, r0);
        half8 h1 = __builtin_bit_cast(half8, r1);
        half8 h2 = __builtin_bit_cast(half8, r2);
        half8 h3 = __builtin_bit_cast(half8, r3);
        #pragma unroll
        for (int k = 0; k < 8; ++k) {
            a0[k] += (float)h0[k];
            a1[k] += (float)h1[k];
            a2[k] += (float)h2[k];
            a3[k] += (float)h3[k];
        }
    }
    for (; j < s1; j += 4) {
        int e0 = esrc[j];
        float4 r0 = ((const float4*)(x + (size_t)e0 * FEAT))[c];
        half8 h0 = __builtin_bit_cast(half8, r0);
        #pragma unroll
        for (int k = 0; k < 8; ++k) a0[k] += (float)h0[k];
    }
    float r[8];
    #pragma unroll
    for (int k = 0; k < 8; ++k) r[k] = (a0[k] + a1[k]) + (a2[k] + a3[k]);
    #pragma unroll
    for (int k = 0; k < 8; ++k) {
        r[k] += __shfl_xor(r[k], 16);
        r[k] += __shfl_xor(r[k], 32);
    }
    if (lane < 16) {
        float sc = nd[v];
        half8 h;
        #pragma unroll
        for (int k = 0; k < 8; ++k) h[k] = (_Float16)(r[k] * sc);
        ((float4*)(m + (size_t)v * FEAT))[c] = __builtin_bit_cast(float4, h);
    }
}

// ---------- GEMM: MFMA f16, m fp16 in (Ar==0), W value+residual; coalesced epilogue ----------
// 32x128 tile, 256 threads (4 waves: 2 row x 2 col), 72KB LDS -> 2 blocks/CU.
// acc = A16*W16 + A16*Wr   (m pre-quantized fp16; W residual kept)
template<int MODE>   // 0: relu*ns -> fp16   1: last layer (fp32 h + threshold)
__global__ __launch_bounds__(256) void gemm_kernel(const _Float16* __restrict__ M,
                                                   const _Float16* __restrict__ w16t,
                                                   const _Float16* __restrict__ wrt,
                                                   const float* __restrict__ bias,
                                                   const float* __restrict__ nsv,
                                                   _Float16* __restrict__ outh,
                                                   float* __restrict__ outf,
                                                   float* __restrict__ out2, int n) {
    __shared__ _Float16 sh[36864];     // 72KB: A16[4096] W16[16384] Wr[16384]
    _Float16* A16s = sh;
    _Float16* W16s = sh + 4096;
    _Float16* Wrs  = sh + 20480;
    int tid = threadIdx.x;
    int r0 = blockIdx.x * 32;

    // stage W (value+residual), XOR-swizzled 16B chunks: chunk ^= (col&7)
    #pragma unroll
    for (int j = 0; j < 8; ++j) {
        int i = tid + j * 256;             // 2048 float4 per array
        int col = i >> 4, ch = i & 15;
        int d = col * 16 + (ch ^ (col & 7));
        ((float4*)W16s)[d] = ((const float4*)w16t)[i];
        ((float4*)Wrs)[d]  = ((const float4*)wrt)[i];
    }
    // stage A rows r0..r0+31: fp16 direct, swizzled
    #pragma unroll
    for (int j = 0; j < 2; ++j) {
        int i = tid + j * 256;             // 512 float4 (8 halves each)
        int row = i >> 4, c8 = i & 15;
        int gr = r0 + row;
        float4 v = make_float4(0.f, 0.f, 0.f, 0.f);
        if (gr < n) v = ((const float4*)(M + (size_t)gr * FEAT))[c8];
        int d = row * 128 + ((c8 ^ (row & 7)) << 3);
        *(float4*)(A16s + d) = v;
    }
    __syncthreads();

    int lane = tid & 63;
    int w = tid >> 6;
    int l15 = lane & 15;
    int q = lane >> 4;
    int rbase = (w & 1) * 16 + l15;        // A-frag row
    int cbase = (w >> 1) * 64;             // wave's 64-col strip

    f32x4 acc[4] = {{0.f,0.f,0.f,0.f},{0.f,0.f,0.f,0.f},{0.f,0.f,0.f,0.f},{0.f,0.f,0.f,0.f}};
    #pragma unroll
    for (int ks = 0; ks < 4; ++ks) {
        int chunk = ks * 4 + q;
        int aoff = rbase * 128 + ((chunk ^ (rbase & 7)) << 3);
        half8 a16 = *(const half8*)(A16s + aoff);
        #pragma unroll
        for (int ct = 0; ct < 4; ++ct) {
            int col = cbase + ct * 16 + l15;
            int boff = col * 128 + ((chunk ^ (col & 7)) << 3);
            half8 b16 = *(const half8*)(W16s + boff);
            half8 br  = *(const half8*)(Wrs + boff);
            acc[ct] = __builtin_amdgcn_mfma_f32_16x16x32_f16(a16, b16, acc[ct], 0, 0, 0);
            acc[ct] = __builtin_amdgcn_mfma_f32_16x16x32_f16(a16, br,  acc[ct], 0, 0, 0);
        }
    }

    // epilogue via LDS restage -> coalesced float4 global stores.
    // C/D layout: col=lane&15, row=(lane>>4)*4+reg
    int rloc = (w & 1) * 16 + q * 4;
    __syncthreads();                       // all MFMA reads of sh done; safe to reuse
    if (MODE == 0) {
        _Float16* hstage = sh;             // 32x128 fp16 = 8KB
        float scv[4];
        #pragma unroll
        for (int reg = 0; reg < 4; ++reg) {
            int row = r0 + rloc + reg;
            scv[reg] = (row < n) ? nsv[row] : 1.0f;
        }
        #pragma unroll
        for (int ct = 0; ct < 4; ++ct) {
            int col = cbase + ct * 16 + l15;
            float b = bias[col];
            #pragma unroll
            for (int reg = 0; reg < 4; ++reg) {
                float h = acc[ct][reg] + b;
                h = h > 0.f ? h : 0.f;
                hstage[(rloc + reg) * 128 + col] = (_Float16)(h * scv[reg]);
            }
        }
        __syncthreads();
        #pragma unroll
        for (int j = 0; j < 2; ++j) {
            int i = tid + j * 256;         // 512 float4 (8 halfs each)
            int row = i >> 4, c16 = i & 15;
            if (r0 + row < n)
                ((float4*)(outh + (size_t)(r0 + row) * FEAT))[c16] =
                    ((const float4*)hstage)[i];
        }
    } else {
        float* fstage = (float*)sh;        // 32x128 fp32 = 16KB
        #pragma unroll
        for (int ct = 0; ct < 4; ++ct) {
            int col = cbase + ct * 16 + l15;
            float b = bias[col];
            #pragma unroll
            for (int reg = 0; reg < 4; ++reg) {
                float h = acc[ct][reg] + b;
                h = h > 0.f ? h : 0.f;
                fstage[(rloc + reg) * 128 + col] = h;
            }
        }
        __syncthreads();
        #pragma unroll
        for (int j = 0; j < 4; ++j) {
            int i = tid + j * 256;         // 1024 float4
            int row = i >> 5, c8 = i & 31;
            if (r0 + row < n) {
                float4 hv = ((const float4*)fstage)[i];
                ((float4*)(outf + (size_t)(r0 + row) * FEAT))[c8] = hv;
                float4 cv;
                cv.x = hv.x >= 0.5f ? 1.f : 0.f; cv.y = hv.y >= 0.5f ? 1.f : 0.f;
                cv.z = hv.z >= 0.5f ? 1.f : 0.f; cv.w = hv.w >= 0.5f ? 1.f : 0.f;
                ((float4*)(out2 + (size_t)(r0 + row) * FEAT))[c8] = cv;
            }
        }
    }
}

extern "C" void kernel_launch(void* const* d_in, const int* in_sizes, int n_in,
                              void* d_out, int out_size, void* d_ws, size_t ws_size,
                              hipStream_t stream) {
    const float* in_feat = (const float*)d_in[0];
    const int*   src     = (const int*)d_in[1];
    const int*   dst     = (const int*)d_in[2];
    const float* W[5] = {(const float*)d_in[3], (const float*)d_in[5], (const float*)d_in[7],
                         (const float*)d_in[9], (const float*)d_in[11]};
    const float* B[5] = {(const float*)d_in[4], (const float*)d_in[6], (const float*)d_in[8],
                         (const float*)d_in[10], (const float*)d_in[12]};
    const int E = in_sizes[1];
    const int N = in_sizes[0] / FEAT;
    const size_t MTOT = (size_t)NPC * NSLICE;         // 3,276,800

    char* ws = (char*)d_ws;
    size_t off = 0;
    auto alloc = [&](size_t bytes) { size_t o = off; off += (bytes + 255) & ~size_t(255); return o; };
    unsigned* partialD = (unsigned*)(ws + alloc(MTOT * 2));
    size_t    pS_off   = alloc(MTOT * 2);
    unsigned* partialS = (unsigned*)(ws + pS_off);
    int*      esrc     = (int*)(ws + pS_off);          // aliases partialS (dead after prep1)
    int*      cursorVT = (int*)(ws + alloc(MTOT * 4));
    _Float16* xh       = (_Float16*)(ws + alloc((size_t)N * FEAT * 2));
    _Float16* mh       = (_Float16*)(ws + alloc((size_t)N * FEAT * 2));
    float*    ns       = (float*)(ws + alloc((size_t)N * 4));
    float*    nd       = (float*)(ws + alloc((size_t)N * 4));
    int*      offsc    = (int*)(ws + alloc((size_t)(N + 1) * 4));
    int*      blockSums = (int*)(ws + alloc(1024));
    _Float16* w16t     = (_Float16*)(ws + alloc(5 * 16384 * 2));
    _Float16* wrt      = (_Float16*)(ws + alloc(5 * 16384 * 2));

    float* out_h = (float*)d_out;                     // final h
    float* out_c = out_h + (size_t)N * FEAT;          // threshold output

    const int scanBlocks = NPC / 256;                 // 200
    const int psBlocks = (N * (FEAT / 8) + 255) / 256; // 3125

    hist_kernel<<<2 * NSLICE, 1024, (NPC / 2) * 4, stream>>>(src, dst, partialD, partialS, E);
    prep1_kernel<<<scanBlocks + 320, 256, 0, stream>>>((const unsigned short*)partialD,
                                                       (const unsigned short*)partialS,
                                                       blockSums, ns, nd,
                                                       W[0], W[1], W[2], W[3], W[4],
                                                       w16t, wrt, N, scanBlocks);
    prep2_kernel<<<scanBlocks + psBlocks, 256, 0, stream>>>((const unsigned short*)partialD,
                                                            blockSums, cursorVT, offsc,
                                                            in_feat, ns, xh, N, scanBlocks);
    fill_kernel<<<(NPC / RANGE_F) * NSLICE, 1024, RANGE_F * 4, stream>>>(src, dst, cursorVT,
                                                                         esrc, E);

    const int agg_blocks = (int)(((size_t)N * 64 + 255) / 256);   // 12500
    const int gemm_blocks = (N + 31) / 32;                        // 1563

    for (int l = 0; l < 5; ++l) {
        agg_kernel<<<agg_blocks, 256, 0, stream>>>(xh, offsc, esrc, nd, mh, N);
        if (l < 4)
            gemm_kernel<0><<<gemm_blocks, 256, 0, stream>>>(mh, w16t + (size_t)l * 16384,
                                                            wrt + (size_t)l * 16384, B[l], ns,
                                                            xh, nullptr, nullptr, N);
        else
            gemm_kernel<1><<<gemm_blocks, 256, 0, stream>>>(mh, w16t + (size_t)l * 16384,
                                                            wrt + (size_t)l * 16384, B[l], nullptr,
                                                            nullptr, out_h, out_c, N);
    }
}